// Round 1
// baseline (853.058 us; speedup 1.0000x reference)
//
#include <hip/hip_runtime.h>
#include <math.h>

typedef unsigned short u16;
typedef __attribute__((ext_vector_type(8))) short bf16x8;
typedef __attribute__((ext_vector_type(4))) float f32x4;

#define MFMA16(a, b, c) __builtin_amdgcn_mfma_f32_16x16x32_bf16((a), (b), (c), 0, 0, 0)

__device__ __forceinline__ u16 f2bf(float f) {
    union { float f; unsigned u; } v; v.f = f;
    unsigned u = v.u;
    unsigned r = (u + 0x7FFFu + ((u >> 16) & 1u)) >> 16;
    return (u16)r;
}
__device__ __forceinline__ float bf2f(u16 h) {
    union { unsigned u; float f; } v; v.u = ((unsigned)h) << 16;
    return v.f;
}

// ---------------- weight transpose + fp32->bf16 convert ----------------
// src: fp32 [K][N] row-major  ->  dst: bf16 [N][K] row-major
__global__ __launch_bounds__(256) void transpose_cvt(const float* __restrict__ src,
                                                     u16* __restrict__ dst, int K, int N) {
    __shared__ float tile[64][65];
    int n0 = blockIdx.x * 64, k0 = blockIdx.y * 64;
    int tx = threadIdx.x & 63, ty = threadIdx.x >> 6;
    #pragma unroll
    for (int i = ty; i < 64; i += 4)
        tile[i][tx] = src[(size_t)(k0 + i) * N + n0 + tx];
    __syncthreads();
    #pragma unroll
    for (int i = ty; i < 64; i += 4)
        dst[(size_t)(n0 + i) * K + k0 + tx] = f2bf(tile[tx][i]);
}

// ---------------- layernorm: fp32 in -> bf16 out, rows of 512 ----------------
__global__ __launch_bounds__(256) void ln_kernel(const float* __restrict__ in,
                                                 u16* __restrict__ out,
                                                 const float* __restrict__ g,
                                                 const float* __restrict__ b) {
    int row = blockIdx.x;
    const float* rp = in + (size_t)row * 512;
    int t = threadIdx.x;
    float2 v = *(const float2*)(rp + t * 2);
    float s = v.x + v.y;
    float sq = v.x * v.x + v.y * v.y;
    #pragma unroll
    for (int off = 32; off > 0; off >>= 1) {
        s  += __shfl_down(s, off, 64);
        sq += __shfl_down(sq, off, 64);
    }
    __shared__ float red[8];
    __shared__ float stat[2];
    int wid = t >> 6;
    if ((t & 63) == 0) { red[wid] = s; red[wid + 4] = sq; }
    __syncthreads();
    if (t == 0) {
        float S = red[0] + red[1] + red[2] + red[3];
        float Q = red[4] + red[5] + red[6] + red[7];
        float mu = S * (1.0f / 512.0f);
        float var = Q * (1.0f / 512.0f) - mu * mu;
        stat[0] = mu;
        stat[1] = rsqrtf(var + 1e-5f);
    }
    __syncthreads();
    float mu = stat[0], inv = stat[1];
    int c = t * 2;
    float2 gv = *(const float2*)(g + c);
    float2 bv = *(const float2*)(b + c);
    ushort2 ov;
    ov.x = f2bf((v.x - mu) * inv * gv.x + bv.x);
    ov.y = f2bf((v.y - mu) * inv * gv.y + bv.y);
    *(ushort2*)(out + (size_t)row * 512 + c) = ov;
}

// ---------------- partial RoPE, in place on q and k ----------------
// layout: [nh=512][s=512][hd=64] bf16.  half=32, 16 real angles + 16 identity.
__global__ __launch_bounds__(256) void rope_kernel(u16* __restrict__ q, u16* __restrict__ k) {
    unsigned tid = blockIdx.x * 256 + threadIdx.x;   // 0..524287
    u16* base = (tid >> 18) ? k : q;
    unsigned row = tid & 262143;                     // nh*512 + s
    int s = row & 511;
    u16* p = base + (size_t)row * 64;
    u16 buf[64], obuf[64];
    #pragma unroll
    for (int i = 0; i < 8; ++i) *(uint4*)&buf[i * 8] = *(const uint4*)(p + i * 8);
    float fs = (float)s;
    #pragma unroll
    for (int d = 0; d < 32; ++d) {
        float sn, cs;
        if (d < 16) {
            // 1/timescale[d] = 10000^(-d/32) = exp(-d * ln(10000)/32)
            float ang = fs * __expf((float)d * -0.28782313662425572f);
            sn = sinf(ang); cs = cosf(ang);
        } else { sn = 0.f; cs = 1.f; }
        float x1 = bf2f(buf[d]), x2 = bf2f(buf[d + 32]);
        obuf[d]      = f2bf(x1 * cs - x2 * sn);
        obuf[d + 32] = f2bf(x2 * cs + x1 * sn);
    }
    #pragma unroll
    for (int i = 0; i < 8; ++i) *(uint4*)(p + i * 8) = *(const uint4*)&obuf[i * 8];
}

// ---------------- bf16 MFMA GEMM, 128x128 tile, BK=32 ----------------
// A: bf16 [M][K] row-major; Bt: bf16 [N][K] row-major (pre-transposed weight).
// MODE 0: out bf16 head-layout (q), v=(acc+bias)*scale
// MODE 1: out bf16 head-layout (k), v=acc+bias
// MODE 2: out bf16 transposed head-layout (v^T), v=acc+bias
// MODE 3: out fp32 row-major, v=acc+bias+res
// MODE 4: out bf16 row-major, v=gelu(acc+bias)
template<int MODE>
__global__ __launch_bounds__(256) void gemm_kernel(
    const u16* __restrict__ A, const u16* __restrict__ Bt,
    const float* __restrict__ bias, const float* __restrict__ res,
    void* __restrict__ outp, int M, int N, int K, float scale)
{
    __shared__ u16 lA[128][40];   // +8 pad: bank stride 20 -> <=2-way (free)
    __shared__ u16 lB[128][40];
    int m0 = blockIdx.y * 128, n0 = blockIdx.x * 128;
    int t = threadIdx.x;
    int wid = t >> 6, lane = t & 63, lm = lane & 15, lq = lane >> 4;
    int wm = (wid >> 1) * 64, wn = (wid & 1) * 64;
    const f32x4 zero = {0.f, 0.f, 0.f, 0.f};
    f32x4 acc[4][4];
    #pragma unroll
    for (int i = 0; i < 4; ++i)
        #pragma unroll
        for (int j = 0; j < 4; ++j) acc[i][j] = zero;

    for (int k0 = 0; k0 < K; k0 += 32) {
        #pragma unroll
        for (int p = 0; p < 2; ++p) {
            int idx = p * 256 + t, row = idx >> 2, c = (idx & 3) * 8;
            *(uint4*)&lA[row][c] = *(const uint4*)(A + (size_t)(m0 + row) * K + k0 + c);
            *(uint4*)&lB[row][c] = *(const uint4*)(Bt + (size_t)(n0 + row) * K + k0 + c);
        }
        __syncthreads();
        bf16x8 af[4], bg[4];
        #pragma unroll
        for (int i = 0; i < 4; ++i) af[i] = *(const bf16x8*)&lA[wm + i * 16 + lm][lq * 8];
        #pragma unroll
        for (int i = 0; i < 4; ++i) bg[i] = *(const bf16x8*)&lB[wn + i * 16 + lm][lq * 8];
        #pragma unroll
        for (int i = 0; i < 4; ++i)
            #pragma unroll
            for (int j = 0; j < 4; ++j)
                acc[i][j] = MFMA16(af[i], bg[j], acc[i][j]);
        __syncthreads();
    }
    // epilogue. C-layout: row = lq*4 + r, col = lm (verified m89/m91)
    #pragma unroll
    for (int i = 0; i < 4; ++i) {
        #pragma unroll
        for (int j = 0; j < 4; ++j) {
            int gn = n0 + wn + j * 16 + lm;
            float bv = bias[gn];
            #pragma unroll
            for (int r = 0; r < 4; ++r) {
                int gm = m0 + wm + i * 16 + lq * 4 + r;
                float v = acc[i][j][r] + bv;
                if (MODE == 0 || MODE == 1) {
                    if (MODE == 0) v *= scale;
                    size_t idx = ((size_t)(gm >> 9)) * 262144 + (size_t)(gn >> 6) * 32768
                               + (size_t)(gm & 511) * 64 + (gn & 63);
                    ((u16*)outp)[idx] = f2bf(v);
                } else if (MODE == 2) {
                    size_t idx = ((size_t)(gm >> 9)) * 262144 + (size_t)(gn >> 6) * 32768
                               + (size_t)(gn & 63) * 512 + (gm & 511);
                    ((u16*)outp)[idx] = f2bf(v);
                } else if (MODE == 3) {
                    size_t idx = (size_t)gm * N + gn;
                    ((float*)outp)[idx] = v + res[idx];
                } else {
                    float gl = 0.5f * v * (1.f + erff(v * 0.70710678118654752f));
                    ((u16*)outp)[(size_t)gm * N + gn] = f2bf(gl);
                }
            }
        }
    }
}

// ---------------- flash-style MFMA attention ----------------
// q,k: bf16 [nh][s=512][hd=64]; vt: bf16 [nh][hd=64][s=512]
// o out: bf16 [32768][512] row-major (proj layout)
__global__ __launch_bounds__(256) void attn_kernel(
    const u16* __restrict__ q, const u16* __restrict__ k,
    const u16* __restrict__ vt, u16* __restrict__ o)
{
    int qt = blockIdx.x;   // 0..7  (64-row q tile)
    int nh = blockIdx.y;   // 0..511
    const u16* Qb = q + (size_t)nh * 32768 + (size_t)qt * 4096;
    const u16* Kb = k + (size_t)nh * 32768;
    const u16* Vb = vt + (size_t)nh * 32768;
    __shared__ u16 lQ[64][72], lK[64][72], lV[64][72];
    __shared__ u16 lP[4][16][72];
    int t = threadIdx.x, wid = t >> 6, lane = t & 63, lm = lane & 15, lq = lane >> 4;

    #pragma unroll
    for (int p = 0; p < 2; ++p) {
        int idx = p * 256 + t, row = idx >> 3, ch = (idx & 7) * 8;
        *(uint4*)&lQ[row][ch] = *(const uint4*)(Qb + (size_t)row * 64 + ch);
    }
    const f32x4 zero = {0.f, 0.f, 0.f, 0.f};
    f32x4 Oacc[4];
    #pragma unroll
    for (int i = 0; i < 4; ++i) Oacc[i] = zero;
    float mo[4] = {-INFINITY, -INFINITY, -INFINITY, -INFINITY};
    float l[4]  = {0.f, 0.f, 0.f, 0.f};

    for (int kt = 0; kt < 8; ++kt) {
        #pragma unroll
        for (int p = 0; p < 2; ++p) {
            int idx = p * 256 + t, row = idx >> 3, ch = (idx & 7) * 8;
            *(uint4*)&lK[row][ch] = *(const uint4*)(Kb + (size_t)(kt * 64 + row) * 64 + ch);
            *(uint4*)&lV[row][ch] = *(const uint4*)(Vb + (size_t)row * 512 + kt * 64 + ch);
        }
        __syncthreads();
        // S = Q Kt  (wave's 16 q rows x 64 keys)
        bf16x8 aq0 = *(const bf16x8*)&lQ[wid * 16 + lm][lq * 8];
        bf16x8 aq1 = *(const bf16x8*)&lQ[wid * 16 + lm][32 + lq * 8];
        f32x4 sc[4];
        #pragma unroll
        for (int jn = 0; jn < 4; ++jn) {
            f32x4 z = zero;
            bf16x8 b0 = *(const bf16x8*)&lK[jn * 16 + lm][lq * 8];
            bf16x8 b1 = *(const bf16x8*)&lK[jn * 16 + lm][32 + lq * 8];
            z = MFMA16(aq0, b0, z);
            z = MFMA16(aq1, b1, z);
            sc[jn] = z;
        }
        // online softmax; row m = lq*4 + r lives in the 16 lanes sharing lq
        float pv[4][4];
        #pragma unroll
        for (int r = 0; r < 4; ++r) {
            float mx = fmaxf(fmaxf(sc[0][r], sc[1][r]), fmaxf(sc[2][r], sc[3][r]));
            #pragma unroll
            for (int off2 = 1; off2 < 16; off2 <<= 1)
                mx = fmaxf(mx, __shfl_xor(mx, off2, 64));
            float mn = fmaxf(mo[r], mx);
            float al = __expf(mo[r] - mn);
            float sum = 0.f;
            #pragma unroll
            for (int jn = 0; jn < 4; ++jn) { pv[jn][r] = __expf(sc[jn][r] - mn); sum += pv[jn][r]; }
            #pragma unroll
            for (int off2 = 1; off2 < 16; off2 <<= 1)
                sum += __shfl_xor(sum, off2, 64);
            l[r] = l[r] * al + sum;
            mo[r] = mn;
            #pragma unroll
            for (int dn = 0; dn < 4; ++dn) Oacc[dn][r] *= al;
        }
        // C-layout -> A-layout via LDS round-trip (per-wave region)
        #pragma unroll
        for (int jn = 0; jn < 4; ++jn)
            #pragma unroll
            for (int r = 0; r < 4; ++r)
                lP[wid][lq * 4 + r][jn * 16 + lm] = f2bf(pv[jn][r]);
        __syncthreads();
        // O += P V
        bf16x8 ap0 = *(const bf16x8*)&lP[wid][lm][lq * 8];
        bf16x8 ap1 = *(const bf16x8*)&lP[wid][lm][32 + lq * 8];
        #pragma unroll
        for (int dn = 0; dn < 4; ++dn) {
            bf16x8 b0 = *(const bf16x8*)&lV[dn * 16 + lm][lq * 8];
            bf16x8 b1 = *(const bf16x8*)&lV[dn * 16 + lm][32 + lq * 8];
            Oacc[dn] = MFMA16(ap0, b0, Oacc[dn]);
            Oacc[dn] = MFMA16(ap1, b1, Oacc[dn]);
        }
        __syncthreads();
    }
    int bc = nh >> 3, h = nh & 7;
    #pragma unroll
    for (int r = 0; r < 4; ++r) {
        float inv = 1.f / l[r];
        int srow = qt * 64 + wid * 16 + lq * 4 + r;
        #pragma unroll
        for (int dn = 0; dn < 4; ++dn) {
            int col = h * 64 + dn * 16 + lm;
            o[((size_t)(bc * 512 + srow)) * 512 + col] = f2bf(Oacc[dn][r] * inv);
        }
    }
}

extern "C" void kernel_launch(void* const* d_in, const int* in_sizes, int n_in,
                              void* d_out, int out_size, void* d_ws, size_t ws_size,
                              hipStream_t stream) {
    const float* x    = (const float*)d_in[0];
    const float* Wq   = (const float*)d_in[1];
    const float* bq   = (const float*)d_in[2];
    const float* Wk   = (const float*)d_in[3];
    const float* bk   = (const float*)d_in[4];
    const float* Wv   = (const float*)d_in[5];
    const float* bv   = (const float*)d_in[6];
    const float* Wo   = (const float*)d_in[7];
    const float* bo   = (const float*)d_in[8];
    const float* ln1g = (const float*)d_in[9];
    const float* ln1b = (const float*)d_in[10];
    const float* ln3g = (const float*)d_in[11];
    const float* ln3b = (const float*)d_in[12];
    const float* W1   = (const float*)d_in[13];
    const float* b1   = (const float*)d_in[14];
    const float* W2   = (const float*)d_in[15];
    const float* b2   = (const float*)d_in[16];

    // ws layout (bytes). q|k|v|o region (134,217,728 B) is recycled for ffa.
    char* ws = (char*)d_ws;
    u16*  hn  = (u16*)(ws + 0ull);            // 33,554,432  (also hn2)
    u16*  qb  = (u16*)(ws + 33554432ull);     // 33,554,432
    u16*  kb  = (u16*)(ws + 67108864ull);     // 33,554,432
    u16*  vb  = (u16*)(ws + 100663296ull);    // 33,554,432
    u16*  ob  = (u16*)(ws + 134217728ull);    // 33,554,432
    u16*  ffa = (u16*)(ws + 33554432ull);     // 134,217,728 (after o consumed)
    float* h1 = (float*)(ws + 167772160ull);  // 67,108,864
    u16*  wqt = (u16*)(ws + 234881024ull);
    u16*  wkt = (u16*)(ws + 235405312ull);
    u16*  wvt = (u16*)(ws + 235929600ull);
    u16*  wot = (u16*)(ws + 236453888ull);
    u16*  w1t = (u16*)(ws + 236978176ull);    // 2,097,152
    u16*  w2t = (u16*)(ws + 239075328ull);    // 2,097,152

    dim3 blk(256);
    transpose_cvt<<<dim3(8, 8),  blk, 0, stream>>>(Wq, wqt, 512, 512);
    transpose_cvt<<<dim3(8, 8),  blk, 0, stream>>>(Wk, wkt, 512, 512);
    transpose_cvt<<<dim3(8, 8),  blk, 0, stream>>>(Wv, wvt, 512, 512);
    transpose_cvt<<<dim3(8, 8),  blk, 0, stream>>>(Wo, wot, 512, 512);
    transpose_cvt<<<dim3(32, 8), blk, 0, stream>>>(W1, w1t, 512, 2048);
    transpose_cvt<<<dim3(8, 32), blk, 0, stream>>>(W2, w2t, 2048, 512);

    ln_kernel<<<32768, blk, 0, stream>>>(x, hn, ln1g, ln1b);

    gemm_kernel<0><<<dim3(4, 256), blk, 0, stream>>>(hn, wqt, bq, nullptr, qb, 32768, 512, 512, 0.125f);
    gemm_kernel<1><<<dim3(4, 256), blk, 0, stream>>>(hn, wkt, bk, nullptr, kb, 32768, 512, 512, 1.f);
    gemm_kernel<2><<<dim3(4, 256), blk, 0, stream>>>(hn, wvt, bv, nullptr, vb, 32768, 512, 512, 1.f);

    rope_kernel<<<2048, blk, 0, stream>>>(qb, kb);

    attn_kernel<<<dim3(8, 512), blk, 0, stream>>>(qb, kb, vb, ob);

    gemm_kernel<3><<<dim3(4, 256), blk, 0, stream>>>(ob, wot, bo, x, h1, 32768, 512, 512, 1.f);

    ln_kernel<<<32768, blk, 0, stream>>>(h1, hn, ln3g, ln3b);

    gemm_kernel<4><<<dim3(16, 256), blk, 0, stream>>>(hn, w1t, b1, nullptr, ffa, 32768, 2048, 512, 1.f);
    gemm_kernel<3><<<dim3(4, 256), blk, 0, stream>>>(ffa, w2t, b2, h1, (float*)d_out, 32768, 512, 2048, 1.f);
}

// Round 2
// 808.885 us; speedup vs baseline: 1.0546x; 1.0546x over previous
//
#include <hip/hip_runtime.h>
#include <math.h>

typedef unsigned short u16;
typedef __attribute__((ext_vector_type(8))) short bf16x8;
typedef __attribute__((ext_vector_type(4))) float f32x4;

#define MFMA16(a, b, c) __builtin_amdgcn_mfma_f32_16x16x32_bf16((a), (b), (c), 0, 0, 0)

__device__ __forceinline__ u16 f2bf(float f) {
    union { float f; unsigned u; } v; v.f = f;
    unsigned u = v.u;
    unsigned r = (u + 0x7FFFu + ((u >> 16) & 1u)) >> 16;
    return (u16)r;
}
__device__ __forceinline__ float bf2f(u16 h) {
    union { unsigned u; float f; } v; v.u = ((unsigned)h) << 16;
    return v.f;
}

// async 16B/lane global->LDS DMA. LDS dest must be lane-linear (base + lane*16).
__device__ __forceinline__ void gl_lds16(const u16* g, u16* l) {
    __builtin_amdgcn_global_load_lds(
        (const __attribute__((address_space(1))) unsigned*)g,
        (__attribute__((address_space(3))) unsigned*)l, 16, 0, 0);
}

// ---------------- weight transpose + fp32->bf16 convert ----------------
// src: fp32 [K][N] row-major  ->  dst: bf16 [N][K] row-major
__global__ __launch_bounds__(256) void transpose_cvt(const float* __restrict__ src,
                                                     u16* __restrict__ dst, int K, int N) {
    __shared__ float tile[64][65];
    int n0 = blockIdx.x * 64, k0 = blockIdx.y * 64;
    int tx = threadIdx.x & 63, ty = threadIdx.x >> 6;
    #pragma unroll
    for (int i = ty; i < 64; i += 4)
        tile[i][tx] = src[(size_t)(k0 + i) * N + n0 + tx];
    __syncthreads();
    #pragma unroll
    for (int i = ty; i < 64; i += 4)
        dst[(size_t)(n0 + i) * K + k0 + tx] = f2bf(tile[tx][i]);
}

// ---------------- layernorm: fp32 in -> bf16 out, rows of 512 ----------------
__global__ __launch_bounds__(256) void ln_kernel(const float* __restrict__ in,
                                                 u16* __restrict__ out,
                                                 const float* __restrict__ g,
                                                 const float* __restrict__ b) {
    int row = blockIdx.x;
    const float* rp = in + (size_t)row * 512;
    int t = threadIdx.x;
    float2 v = *(const float2*)(rp + t * 2);
    float s = v.x + v.y;
    float sq = v.x * v.x + v.y * v.y;
    #pragma unroll
    for (int off = 32; off > 0; off >>= 1) {
        s  += __shfl_down(s, off, 64);
        sq += __shfl_down(sq, off, 64);
    }
    __shared__ float red[8];
    __shared__ float stat[2];
    int wid = t >> 6;
    if ((t & 63) == 0) { red[wid] = s; red[wid + 4] = sq; }
    __syncthreads();
    if (t == 0) {
        float S = red[0] + red[1] + red[2] + red[3];
        float Q = red[4] + red[5] + red[6] + red[7];
        float mu = S * (1.0f / 512.0f);
        float var = Q * (1.0f / 512.0f) - mu * mu;
        stat[0] = mu;
        stat[1] = rsqrtf(var + 1e-5f);
    }
    __syncthreads();
    float mu = stat[0], inv = stat[1];
    int c = t * 2;
    float2 gv = *(const float2*)(g + c);
    float2 bv = *(const float2*)(b + c);
    ushort2 ov;
    ov.x = f2bf((v.x - mu) * inv * gv.x + bv.x);
    ov.y = f2bf((v.y - mu) * inv * gv.y + bv.y);
    *(ushort2*)(out + (size_t)row * 512 + c) = ov;
}

// ---------------- partial RoPE, in place on q and k ----------------
// layout: [nh=512][s=512][hd=64] bf16.  half=32, 16 real angles + 16 identity.
__global__ __launch_bounds__(256) void rope_kernel(u16* __restrict__ q, u16* __restrict__ k) {
    unsigned tid = blockIdx.x * 256 + threadIdx.x;   // 0..524287
    u16* base = (tid >> 18) ? k : q;
    unsigned row = tid & 262143;                     // nh*512 + s
    int s = row & 511;
    u16* p = base + (size_t)row * 64;
    u16 buf[64], obuf[64];
    #pragma unroll
    for (int i = 0; i < 8; ++i) *(uint4*)&buf[i * 8] = *(const uint4*)(p + i * 8);
    float fs = (float)s;
    #pragma unroll
    for (int d = 0; d < 32; ++d) {
        float sn, cs;
        if (d < 16) {
            // 1/timescale[d] = 10000^(-d/32) = exp(-d * ln(10000)/32)
            float ang = fs * __expf((float)d * -0.28782313662425572f);
            sn = sinf(ang); cs = cosf(ang);
        } else { sn = 0.f; cs = 1.f; }
        float x1 = bf2f(buf[d]), x2 = bf2f(buf[d + 32]);
        obuf[d]      = f2bf(x1 * cs - x2 * sn);
        obuf[d + 32] = f2bf(x2 * cs + x1 * sn);
    }
    #pragma unroll
    for (int i = 0; i < 8; ++i) *(uint4*)(p + i * 8) = *(const uint4*)&obuf[i * 8];
}

// ---------------- bf16 MFMA GEMM, 128x128 tile, BK=32, m97 DMA staging ------
// A: bf16 [M][K] row-major; Bt: bf16 [N][K] row-major (pre-transposed weight).
// MODE 0: out bf16 head-layout (q), v=(acc+bias)*scale
// MODE 1: out bf16 head-layout (k), v=acc+bias
// MODE 2: out bf16 transposed head-layout (v^T), v=acc+bias
// MODE 3: out fp32 row-major, v=acc+bias+res
// MODE 4: out bf16 row-major, v=gelu(acc+bias)
template<int MODE>
__global__ __launch_bounds__(256) void gemm_kernel(
    const u16* __restrict__ A, const u16* __restrict__ Bt,
    const float* __restrict__ bias, const float* __restrict__ res,
    void* __restrict__ outp, int M, int N, int K, float scale)
{
    // unpadded: global_load_lds needs lane-linear LDS dest (m104/m108)
    __shared__ u16 lA[128 * 32];
    __shared__ u16 lB[128 * 32];
    int m0 = blockIdx.y * 128, n0 = blockIdx.x * 128;
    int t = threadIdx.x;
    int wid = t >> 6, lane = t & 63, lm = lane & 15, lq = lane >> 4;
    int wm = (wid >> 1) * 64, wn = (wid & 1) * 64;
    const f32x4 zero = {0.f, 0.f, 0.f, 0.f};
    f32x4 acc[4][4];
    #pragma unroll
    for (int i = 0; i < 4; ++i)
        #pragma unroll
        for (int j = 0; j < 4; ++j) acc[i][j] = zero;

    // staging: tile is 8192 B; thread t round p covers bytes p*4096 + t*16
    int f0 = t * 16;                 // byte offset, round 0
    int r0 = f0 >> 6, c0 = (f0 & 63) >> 1;       // row, u16-col within BK
    int f1 = f0 + 4096;
    int r1 = f1 >> 6, c1 = (f1 & 63) >> 1;
    const u16* Abase0 = A + (size_t)(m0 + r0) * K + c0;
    const u16* Abase1 = A + (size_t)(m0 + r1) * K + c1;
    const u16* Bbase0 = Bt + (size_t)(n0 + r0) * K + c0;
    const u16* Bbase1 = Bt + (size_t)(n0 + r1) * K + c1;

    for (int k0 = 0; k0 < K; k0 += 32) {
        gl_lds16(Abase0 + k0, lA + (f0 >> 1));
        gl_lds16(Abase1 + k0, lA + (f1 >> 1));
        gl_lds16(Bbase0 + k0, lB + (f0 >> 1));
        gl_lds16(Bbase1 + k0, lB + (f1 >> 1));
        __syncthreads();   // vmcnt(0) drain + barrier (m97 structure)
        bf16x8 af[4], bg[4];
        #pragma unroll
        for (int i = 0; i < 4; ++i) af[i] = *(const bf16x8*)&lA[(wm + i * 16 + lm) * 32 + lq * 8];
        #pragma unroll
        for (int i = 0; i < 4; ++i) bg[i] = *(const bf16x8*)&lB[(wn + i * 16 + lm) * 32 + lq * 8];
        #pragma unroll
        for (int i = 0; i < 4; ++i)
            #pragma unroll
            for (int j = 0; j < 4; ++j)
                acc[i][j] = MFMA16(af[i], bg[j], acc[i][j]);
        __syncthreads();
    }
    // epilogue. C-layout: row = lq*4 + r, col = lm (verified m89/m91)
    #pragma unroll
    for (int i = 0; i < 4; ++i) {
        #pragma unroll
        for (int j = 0; j < 4; ++j) {
            int gn = n0 + wn + j * 16 + lm;
            float bv = bias[gn];
            #pragma unroll
            for (int r = 0; r < 4; ++r) {
                int gm = m0 + wm + i * 16 + lq * 4 + r;
                float v = acc[i][j][r] + bv;
                if (MODE == 0 || MODE == 1) {
                    if (MODE == 0) v *= scale;
                    size_t idx = ((size_t)(gm >> 9)) * 262144 + (size_t)(gn >> 6) * 32768
                               + (size_t)(gm & 511) * 64 + (gn & 63);
                    ((u16*)outp)[idx] = f2bf(v);
                } else if (MODE == 2) {
                    size_t idx = ((size_t)(gm >> 9)) * 262144 + (size_t)(gn >> 6) * 32768
                               + (size_t)(gn & 63) * 512 + (gm & 511);
                    ((u16*)outp)[idx] = f2bf(v);
                } else if (MODE == 3) {
                    size_t idx = (size_t)gm * N + gn;
                    ((float*)outp)[idx] = v + res[idx];
                } else {
                    float gl = 0.5f * v * (1.f + erff(v * 0.70710678118654752f));
                    ((u16*)outp)[(size_t)gm * N + gn] = f2bf(gl);
                }
            }
        }
    }
}

// ---------------- flash-style MFMA attention ----------------
// q,k: bf16 [nh][s=512][hd=64]; vt: bf16 [nh][hd=64][s=512]
// o out: bf16 [32768][512] row-major (proj layout)
__global__ __launch_bounds__(256) void attn_kernel(
    const u16* __restrict__ q, const u16* __restrict__ k,
    const u16* __restrict__ vt, u16* __restrict__ o)
{
    int qt = blockIdx.x;   // 0..7  (64-row q tile)
    int nh = blockIdx.y;   // 0..511
    const u16* Qb = q + (size_t)nh * 32768 + (size_t)qt * 4096;
    const u16* Kb = k + (size_t)nh * 32768;
    const u16* Vb = vt + (size_t)nh * 32768;
    __shared__ u16 lQ[64][72], lK[64][72], lV[64][72];
    __shared__ u16 lP[4][16][72];
    int t = threadIdx.x, wid = t >> 6, lane = t & 63, lm = lane & 15, lq = lane >> 4;

    #pragma unroll
    for (int p = 0; p < 2; ++p) {
        int idx = p * 256 + t, row = idx >> 3, ch = (idx & 7) * 8;
        *(uint4*)&lQ[row][ch] = *(const uint4*)(Qb + (size_t)row * 64 + ch);
    }
    const f32x4 zero = {0.f, 0.f, 0.f, 0.f};
    f32x4 Oacc[4];
    #pragma unroll
    for (int i = 0; i < 4; ++i) Oacc[i] = zero;
    float mo[4] = {-INFINITY, -INFINITY, -INFINITY, -INFINITY};
    float l[4]  = {0.f, 0.f, 0.f, 0.f};

    for (int kt = 0; kt < 8; ++kt) {
        #pragma unroll
        for (int p = 0; p < 2; ++p) {
            int idx = p * 256 + t, row = idx >> 3, ch = (idx & 7) * 8;
            *(uint4*)&lK[row][ch] = *(const uint4*)(Kb + (size_t)(kt * 64 + row) * 64 + ch);
            *(uint4*)&lV[row][ch] = *(const uint4*)(Vb + (size_t)row * 512 + kt * 64 + ch);
        }
        __syncthreads();
        // S = Q Kt  (wave's 16 q rows x 64 keys)
        bf16x8 aq0 = *(const bf16x8*)&lQ[wid * 16 + lm][lq * 8];
        bf16x8 aq1 = *(const bf16x8*)&lQ[wid * 16 + lm][32 + lq * 8];
        f32x4 sc[4];
        #pragma unroll
        for (int jn = 0; jn < 4; ++jn) {
            f32x4 z = zero;
            bf16x8 b0 = *(const bf16x8*)&lK[jn * 16 + lm][lq * 8];
            bf16x8 b1 = *(const bf16x8*)&lK[jn * 16 + lm][32 + lq * 8];
            z = MFMA16(aq0, b0, z);
            z = MFMA16(aq1, b1, z);
            sc[jn] = z;
        }
        // online softmax; row m = lq*4 + r lives in the 16 lanes sharing lq
        float pv[4][4];
        #pragma unroll
        for (int r = 0; r < 4; ++r) {
            float mx = fmaxf(fmaxf(sc[0][r], sc[1][r]), fmaxf(sc[2][r], sc[3][r]));
            #pragma unroll
            for (int off2 = 1; off2 < 16; off2 <<= 1)
                mx = fmaxf(mx, __shfl_xor(mx, off2, 64));
            float mn = fmaxf(mo[r], mx);
            float al = __expf(mo[r] - mn);
            float sum = 0.f;
            #pragma unroll
            for (int jn = 0; jn < 4; ++jn) { pv[jn][r] = __expf(sc[jn][r] - mn); sum += pv[jn][r]; }
            #pragma unroll
            for (int off2 = 1; off2 < 16; off2 <<= 1)
                sum += __shfl_xor(sum, off2, 64);
            l[r] = l[r] * al + sum;
            mo[r] = mn;
            #pragma unroll
            for (int dn = 0; dn < 4; ++dn) Oacc[dn][r] *= al;
        }
        // C-layout -> A-layout via LDS round-trip (per-wave region)
        #pragma unroll
        for (int jn = 0; jn < 4; ++jn)
            #pragma unroll
            for (int r = 0; r < 4; ++r)
                lP[wid][lq * 4 + r][jn * 16 + lm] = f2bf(pv[jn][r]);
        __syncthreads();
        // O += P V
        bf16x8 ap0 = *(const bf16x8*)&lP[wid][lm][lq * 8];
        bf16x8 ap1 = *(const bf16x8*)&lP[wid][lm][32 + lq * 8];
        #pragma unroll
        for (int dn = 0; dn < 4; ++dn) {
            bf16x8 b0 = *(const bf16x8*)&lV[dn * 16 + lm][lq * 8];
            bf16x8 b1 = *(const bf16x8*)&lV[dn * 16 + lm][32 + lq * 8];
            Oacc[dn] = MFMA16(ap0, b0, Oacc[dn]);
            Oacc[dn] = MFMA16(ap1, b1, Oacc[dn]);
        }
        __syncthreads();
    }
    int bc = nh >> 3, h = nh & 7;
    #pragma unroll
    for (int r = 0; r < 4; ++r) {
        float inv = 1.f / l[r];
        int srow = qt * 64 + wid * 16 + lq * 4 + r;
        #pragma unroll
        for (int dn = 0; dn < 4; ++dn) {
            int col = h * 64 + dn * 16 + lm;
            o[((size_t)(bc * 512 + srow)) * 512 + col] = f2bf(Oacc[dn][r] * inv);
        }
    }
}

extern "C" void kernel_launch(void* const* d_in, const int* in_sizes, int n_in,
                              void* d_out, int out_size, void* d_ws, size_t ws_size,
                              hipStream_t stream) {
    const float* x    = (const float*)d_in[0];
    const float* Wq   = (const float*)d_in[1];
    const float* bq   = (const float*)d_in[2];
    const float* Wk   = (const float*)d_in[3];
    const float* bk   = (const float*)d_in[4];
    const float* Wv   = (const float*)d_in[5];
    const float* bv   = (const float*)d_in[6];
    const float* Wo   = (const float*)d_in[7];
    const float* bo   = (const float*)d_in[8];
    const float* ln1g = (const float*)d_in[9];
    const float* ln1b = (const float*)d_in[10];
    const float* ln3g = (const float*)d_in[11];
    const float* ln3b = (const float*)d_in[12];
    const float* W1   = (const float*)d_in[13];
    const float* b1   = (const float*)d_in[14];
    const float* W2   = (const float*)d_in[15];
    const float* b2   = (const float*)d_in[16];

    // ws layout (bytes). q|k|v|o region (134,217,728 B) is recycled for ffa.
    char* ws = (char*)d_ws;
    u16*  hn  = (u16*)(ws + 0ull);            // 33,554,432  (also hn2)
    u16*  qb  = (u16*)(ws + 33554432ull);     // 33,554,432
    u16*  kb  = (u16*)(ws + 67108864ull);     // 33,554,432
    u16*  vb  = (u16*)(ws + 100663296ull);    // 33,554,432
    u16*  ob  = (u16*)(ws + 134217728ull);    // 33,554,432
    u16*  ffa = (u16*)(ws + 33554432ull);     // 134,217,728 (after o consumed)
    float* h1 = (float*)(ws + 167772160ull);  // 67,108,864
    u16*  wqt = (u16*)(ws + 234881024ull);
    u16*  wkt = (u16*)(ws + 235405312ull);
    u16*  wvt = (u16*)(ws + 235929600ull);
    u16*  wot = (u16*)(ws + 236453888ull);
    u16*  w1t = (u16*)(ws + 236978176ull);    // 2,097,152
    u16*  w2t = (u16*)(ws + 239075328ull);    // 2,097,152

    dim3 blk(256);
    transpose_cvt<<<dim3(8, 8),  blk, 0, stream>>>(Wq, wqt, 512, 512);
    transpose_cvt<<<dim3(8, 8),  blk, 0, stream>>>(Wk, wkt, 512, 512);
    transpose_cvt<<<dim3(8, 8),  blk, 0, stream>>>(Wv, wvt, 512, 512);
    transpose_cvt<<<dim3(8, 8),  blk, 0, stream>>>(Wo, wot, 512, 512);
    transpose_cvt<<<dim3(32, 8), blk, 0, stream>>>(W1, w1t, 512, 2048);
    transpose_cvt<<<dim3(8, 32), blk, 0, stream>>>(W2, w2t, 2048, 512);

    ln_kernel<<<32768, blk, 0, stream>>>(x, hn, ln1g, ln1b);

    gemm_kernel<0><<<dim3(4, 256), blk, 0, stream>>>(hn, wqt, bq, nullptr, qb, 32768, 512, 512, 0.125f);
    gemm_kernel<1><<<dim3(4, 256), blk, 0, stream>>>(hn, wkt, bk, nullptr, kb, 32768, 512, 512, 1.f);
    gemm_kernel<2><<<dim3(4, 256), blk, 0, stream>>>(hn, wvt, bv, nullptr, vb, 32768, 512, 512, 1.f);

    rope_kernel<<<2048, blk, 0, stream>>>(qb, kb);

    attn_kernel<<<dim3(8, 512), blk, 0, stream>>>(qb, kb, vb, ob);

    gemm_kernel<3><<<dim3(4, 256), blk, 0, stream>>>(ob, wot, bo, x, h1, 32768, 512, 512, 1.f);

    ln_kernel<<<32768, blk, 0, stream>>>(h1, ln3g ? hn : hn, ln3g, ln3b);

    gemm_kernel<4><<<dim3(16, 256), blk, 0, stream>>>(hn, w1t, b1, nullptr, ffa, 32768, 2048, 512, 1.f);
    gemm_kernel<3><<<dim3(4, 256), blk, 0, stream>>>(ffa, w2t, b2, h1, (float*)d_out, 32768, 512, 2048, 1.f);
}

// Round 3
// 695.670 us; speedup vs baseline: 1.2262x; 1.1627x over previous
//
#include <hip/hip_runtime.h>
#include <math.h>

typedef unsigned short u16;
typedef __attribute__((ext_vector_type(8))) short bf16x8;
typedef __attribute__((ext_vector_type(4))) float f32x4;

#define MFMA16(a, b, c) __builtin_amdgcn_mfma_f32_16x16x32_bf16((a), (b), (c), 0, 0, 0)

__device__ __forceinline__ u16 f2bf(float f) {
    union { float f; unsigned u; } v; v.f = f;
    unsigned u = v.u;
    unsigned r = (u + 0x7FFFu + ((u >> 16) & 1u)) >> 16;
    return (u16)r;
}
__device__ __forceinline__ float bf2f(u16 h) {
    union { unsigned u; float f; } v; v.u = ((unsigned)h) << 16;
    return v.f;
}

// async 16B/lane global->LDS DMA. LDS dest must be lane-linear (base + lane*16).
__device__ __forceinline__ void gl_lds16(const u16* g, u16* l) {
    __builtin_amdgcn_global_load_lds(
        (const __attribute__((address_space(1))) unsigned*)g,
        (__attribute__((address_space(3))) unsigned*)l, 16, 0, 0);
}

// ---------------- weight transpose + fp32->bf16 convert ----------------
__global__ __launch_bounds__(256) void transpose_cvt(const float* __restrict__ src,
                                                     u16* __restrict__ dst, int K, int N) {
    __shared__ float tile[64][65];
    int n0 = blockIdx.x * 64, k0 = blockIdx.y * 64;
    int tx = threadIdx.x & 63, ty = threadIdx.x >> 6;
    #pragma unroll
    for (int i = ty; i < 64; i += 4)
        tile[i][tx] = src[(size_t)(k0 + i) * N + n0 + tx];
    __syncthreads();
    #pragma unroll
    for (int i = ty; i < 64; i += 4)
        dst[(size_t)(n0 + i) * K + k0 + tx] = f2bf(tile[tx][i]);
}

// ---------------- layernorm: fp32 in -> bf16 out, rows of 512 ----------------
__global__ __launch_bounds__(256) void ln_kernel(const float* __restrict__ in,
                                                 u16* __restrict__ out,
                                                 const float* __restrict__ g,
                                                 const float* __restrict__ b) {
    int row = blockIdx.x;
    const float* rp = in + (size_t)row * 512;
    int t = threadIdx.x;
    float2 v = *(const float2*)(rp + t * 2);
    float s = v.x + v.y;
    float sq = v.x * v.x + v.y * v.y;
    #pragma unroll
    for (int off = 32; off > 0; off >>= 1) {
        s  += __shfl_down(s, off, 64);
        sq += __shfl_down(sq, off, 64);
    }
    __shared__ float red[8];
    __shared__ float stat[2];
    int wid = t >> 6;
    if ((t & 63) == 0) { red[wid] = s; red[wid + 4] = sq; }
    __syncthreads();
    if (t == 0) {
        float S = red[0] + red[1] + red[2] + red[3];
        float Q = red[4] + red[5] + red[6] + red[7];
        float mu = S * (1.0f / 512.0f);
        float var = Q * (1.0f / 512.0f) - mu * mu;
        stat[0] = mu;
        stat[1] = rsqrtf(var + 1e-5f);
    }
    __syncthreads();
    float mu = stat[0], inv = stat[1];
    int c = t * 2;
    float2 gv = *(const float2*)(g + c);
    float2 bv = *(const float2*)(b + c);
    ushort2 ov;
    ov.x = f2bf((v.x - mu) * inv * gv.x + bv.x);
    ov.y = f2bf((v.y - mu) * inv * gv.y + bv.y);
    *(ushort2*)(out + (size_t)row * 512 + c) = ov;
}

// ---------------- bf16 MFMA GEMM, 128x128 tile, BK=64, DMA staging ----------
// XCD-swizzled: blocks sharing an A-tile land on one XCD (L2 reuse).
// A: bf16 [M][K] row-major; Bt: bf16 [N][K] row-major (pre-transposed weight).
// MODE 0: out bf16 head-layout + RoPE (q), v=(acc+bias)*scale
// MODE 1: out bf16 head-layout + RoPE (k)
// MODE 2: out bf16 transposed head-layout (v^T), v=acc+bias
// MODE 3: out fp32 row-major, v=acc+bias+res
// MODE 4: out bf16 row-major, v=gelu(acc+bias)
template<int MODE>
__global__ __launch_bounds__(256) void gemm_kernel(
    const u16* __restrict__ A, const u16* __restrict__ Bt,
    const float* __restrict__ bias, const float* __restrict__ res,
    void* __restrict__ outp, int M, int N, int K, float scale)
{
    __shared__ u16 lA[2][128 * 32];   // two BK=32 halves (proven m97 bank layout)
    __shared__ u16 lB[2][128 * 32];
    // ---- XCD swizzle: flat%8 = XCD (round-robin dispatch heuristic).
    // groups of gridDim.x consecutive slots on one XCD share one m-tile.
    int flat = blockIdx.y * gridDim.x + blockIdx.x;
    int xcd = flat & 7, slot = flat >> 3;
    int nb = gridDim.x;
    int mper = gridDim.y >> 3;
    int mt = xcd * mper + slot / nb;
    int nt = slot % nb;
    int m0 = mt * 128, n0 = nt * 128;

    int t = threadIdx.x;
    int wid = t >> 6, lane = t & 63, lm = lane & 15, lq = lane >> 4;
    int wm = (wid >> 1) * 64, wn = (wid & 1) * 64;
    const f32x4 zero = {0.f, 0.f, 0.f, 0.f};
    f32x4 acc[4][4];
    #pragma unroll
    for (int i = 0; i < 4; ++i)
        #pragma unroll
        for (int j = 0; j < 4; ++j) acc[i][j] = zero;

    // staging: per half (8192 B) 2 rounds of 256 lanes x 16 B.
    // round p covers rows p*64 + t/4, cols (t&3)*8 (u16) within the half.
    int rr = t >> 2, cc = (t & 3) * 8;
    const u16* Ab = A + (size_t)(m0 + rr) * K + cc;
    const u16* Bb = Bt + (size_t)(n0 + rr) * K + cc;
    size_t pstep = (size_t)64 * K;
    int ldst = t * 8;   // u16 offset, +2048 per round

    for (int k0 = 0; k0 < K; k0 += 64) {
        #pragma unroll
        for (int h = 0; h < 2; ++h) {
            #pragma unroll
            for (int p = 0; p < 2; ++p) {
                gl_lds16(Ab + k0 + h * 32 + p * pstep, lA[h] + p * 2048 + ldst);
                gl_lds16(Bb + k0 + h * 32 + p * pstep, lB[h] + p * 2048 + ldst);
            }
        }
        __syncthreads();
        #pragma unroll
        for (int h = 0; h < 2; ++h) {
            bf16x8 af[4], bg[4];
            #pragma unroll
            for (int i = 0; i < 4; ++i) af[i] = *(const bf16x8*)&lA[h][(wm + i * 16 + lm) * 32 + lq * 8];
            #pragma unroll
            for (int i = 0; i < 4; ++i) bg[i] = *(const bf16x8*)&lB[h][(wn + i * 16 + lm) * 32 + lq * 8];
            #pragma unroll
            for (int i = 0; i < 4; ++i)
                #pragma unroll
                for (int j = 0; j < 4; ++j)
                    acc[i][j] = MFMA16(af[i], bg[j], acc[i][j]);
        }
        __syncthreads();
    }

    // epilogue. C-layout: row = lq*4 + r, col = lm (verified m89/m91)
    if (MODE == 0 || MODE == 1) {
        // head layout [bc][h][s][d]; d = (gn&63) = j*16+lm.  RoPE pairs
        // (d, d+32) = (acc[i][0],acc[i][2]) rotated (d=lm<16); j=1/3 identity.
        float bv0 = bias[n0 + wn + 0 * 16 + lm];
        float bv1 = bias[n0 + wn + 1 * 16 + lm];
        float bv2 = bias[n0 + wn + 2 * 16 + lm];
        float bv3 = bias[n0 + wn + 3 * 16 + lm];
        float its = __expf((float)lm * -0.28782313662425572f);  // 10000^(-lm/32)
        #pragma unroll
        for (int i = 0; i < 4; ++i) {
            #pragma unroll
            for (int r = 0; r < 4; ++r) {
                int gm = m0 + wm + i * 16 + lq * 4 + r;
                int s = gm & 511;
                float ang = (float)s * its;
                float sn = __sinf(ang), cs = __cosf(ang);
                float x1 = acc[i][0][r] + bv0;
                float x2 = acc[i][2][r] + bv2;
                float y0 = x1 * cs - x2 * sn;
                float y2 = x2 * cs + x1 * sn;
                float y1 = acc[i][1][r] + bv1;
                float y3 = acc[i][3][r] + bv3;
                if (MODE == 0) { y0 *= scale; y1 *= scale; y2 *= scale; y3 *= scale; }
                size_t base = ((size_t)(gm >> 9)) * 262144 + (size_t)((n0 + wn) >> 6) * 32768
                            + (size_t)s * 64 + lm;
                ((u16*)outp)[base +  0] = f2bf(y0);
                ((u16*)outp)[base + 16] = f2bf(y1);
                ((u16*)outp)[base + 32] = f2bf(y2);
                ((u16*)outp)[base + 48] = f2bf(y3);
            }
        }
    } else {
        #pragma unroll
        for (int i = 0; i < 4; ++i) {
            #pragma unroll
            for (int j = 0; j < 4; ++j) {
                int gn = n0 + wn + j * 16 + lm;
                float bv = bias[gn];
                #pragma unroll
                for (int r = 0; r < 4; ++r) {
                    int gm = m0 + wm + i * 16 + lq * 4 + r;
                    float v = acc[i][j][r] + bv;
                    if (MODE == 2) {
                        size_t idx = ((size_t)(gm >> 9)) * 262144 + (size_t)(gn >> 6) * 32768
                                   + (size_t)(gn & 63) * 512 + (gm & 511);
                        ((u16*)outp)[idx] = f2bf(v);
                    } else if (MODE == 3) {
                        size_t idx = (size_t)gm * N + gn;
                        ((float*)outp)[idx] = v + res[idx];
                    } else {
                        float gl = 0.5f * v * (1.f + erff(v * 0.70710678118654752f));
                        ((u16*)outp)[(size_t)gm * N + gn] = f2bf(gl);
                    }
                }
            }
        }
    }
}

// ---------------- flash-style MFMA attention ----------------
// q,k: bf16 [nh][s=512][hd=64]; vt: bf16 [nh][hd=64][s=512]
// o out: bf16 [32768][512] row-major (proj layout)
__global__ __launch_bounds__(256) void attn_kernel(
    const u16* __restrict__ q, const u16* __restrict__ k,
    const u16* __restrict__ vt, u16* __restrict__ o)
{
    // swizzle: 8 q-tiles of one head on one XCD (share K/V in L2)
    int flat = blockIdx.y * gridDim.x + blockIdx.x;
    int xcd = flat & 7, slot = flat >> 3;
    int nh = xcd * 64 + (slot >> 3);
    int qt = slot & 7;
    const u16* Qb = q + (size_t)nh * 32768 + (size_t)qt * 4096;
    const u16* Kb = k + (size_t)nh * 32768;
    const u16* Vb = vt + (size_t)nh * 32768;
    __shared__ u16 lQ[64][72], lK[64][72], lV[64][72];
    __shared__ u16 lP[4][16][72];
    int t = threadIdx.x, wid = t >> 6, lane = t & 63, lm = lane & 15, lq = lane >> 4;

    #pragma unroll
    for (int p = 0; p < 2; ++p) {
        int idx = p * 256 + t, row = idx >> 3, ch = (idx & 7) * 8;
        *(uint4*)&lQ[row][ch] = *(const uint4*)(Qb + (size_t)row * 64 + ch);
    }
    const f32x4 zero = {0.f, 0.f, 0.f, 0.f};
    f32x4 Oacc[4];
    #pragma unroll
    for (int i = 0; i < 4; ++i) Oacc[i] = zero;
    float mo[4] = {-INFINITY, -INFINITY, -INFINITY, -INFINITY};
    float l[4]  = {0.f, 0.f, 0.f, 0.f};

    for (int kt = 0; kt < 8; ++kt) {
        #pragma unroll
        for (int p = 0; p < 2; ++p) {
            int idx = p * 256 + t, row = idx >> 3, ch = (idx & 7) * 8;
            *(uint4*)&lK[row][ch] = *(const uint4*)(Kb + (size_t)(kt * 64 + row) * 64 + ch);
            *(uint4*)&lV[row][ch] = *(const uint4*)(Vb + (size_t)row * 512 + kt * 64 + ch);
        }
        __syncthreads();
        bf16x8 aq0 = *(const bf16x8*)&lQ[wid * 16 + lm][lq * 8];
        bf16x8 aq1 = *(const bf16x8*)&lQ[wid * 16 + lm][32 + lq * 8];
        f32x4 sc[4];
        #pragma unroll
        for (int jn = 0; jn < 4; ++jn) {
            f32x4 z = zero;
            bf16x8 b0 = *(const bf16x8*)&lK[jn * 16 + lm][lq * 8];
            bf16x8 b1 = *(const bf16x8*)&lK[jn * 16 + lm][32 + lq * 8];
            z = MFMA16(aq0, b0, z);
            z = MFMA16(aq1, b1, z);
            sc[jn] = z;
        }
        float pv[4][4];
        #pragma unroll
        for (int r = 0; r < 4; ++r) {
            float mx = fmaxf(fmaxf(sc[0][r], sc[1][r]), fmaxf(sc[2][r], sc[3][r]));
            #pragma unroll
            for (int off2 = 1; off2 < 16; off2 <<= 1)
                mx = fmaxf(mx, __shfl_xor(mx, off2, 64));
            float mn = fmaxf(mo[r], mx);
            float al = __expf(mo[r] - mn);
            float sum = 0.f;
            #pragma unroll
            for (int jn = 0; jn < 4; ++jn) { pv[jn][r] = __expf(sc[jn][r] - mn); sum += pv[jn][r]; }
            #pragma unroll
            for (int off2 = 1; off2 < 16; off2 <<= 1)
                sum += __shfl_xor(sum, off2, 64);
            l[r] = l[r] * al + sum;
            mo[r] = mn;
            #pragma unroll
            for (int dn = 0; dn < 4; ++dn) Oacc[dn][r] *= al;
        }
        #pragma unroll
        for (int jn = 0; jn < 4; ++jn)
            #pragma unroll
            for (int r = 0; r < 4; ++r)
                lP[wid][lq * 4 + r][jn * 16 + lm] = f2bf(pv[jn][r]);
        __syncthreads();
        bf16x8 ap0 = *(const bf16x8*)&lP[wid][lm][lq * 8];
        bf16x8 ap1 = *(const bf16x8*)&lP[wid][lm][32 + lq * 8];
        #pragma unroll
        for (int dn = 0; dn < 4; ++dn) {
            bf16x8 b0 = *(const bf16x8*)&lV[dn * 16 + lm][lq * 8];
            bf16x8 b1 = *(const bf16x8*)&lV[dn * 16 + lm][32 + lq * 8];
            Oacc[dn] = MFMA16(ap0, b0, Oacc[dn]);
            Oacc[dn] = MFMA16(ap1, b1, Oacc[dn]);
        }
        __syncthreads();
    }
    int bc = nh >> 3, h = nh & 7;
    #pragma unroll
    for (int r = 0; r < 4; ++r) {
        float inv = 1.f / l[r];
        int srow = qt * 64 + wid * 16 + lq * 4 + r;
        #pragma unroll
        for (int dn = 0; dn < 4; ++dn) {
            int col = h * 64 + dn * 16 + lm;
            o[((size_t)(bc * 512 + srow)) * 512 + col] = f2bf(Oacc[dn][r] * inv);
        }
    }
}

extern "C" void kernel_launch(void* const* d_in, const int* in_sizes, int n_in,
                              void* d_out, int out_size, void* d_ws, size_t ws_size,
                              hipStream_t stream) {
    const float* x    = (const float*)d_in[0];
    const float* Wq   = (const float*)d_in[1];
    const float* bq   = (const float*)d_in[2];
    const float* Wk   = (const float*)d_in[3];
    const float* bk   = (const float*)d_in[4];
    const float* Wv   = (const float*)d_in[5];
    const float* bv   = (const float*)d_in[6];
    const float* Wo   = (const float*)d_in[7];
    const float* bo   = (const float*)d_in[8];
    const float* ln1g = (const float*)d_in[9];
    const float* ln1b = (const float*)d_in[10];
    const float* ln3g = (const float*)d_in[11];
    const float* ln3b = (const float*)d_in[12];
    const float* W1   = (const float*)d_in[13];
    const float* b1   = (const float*)d_in[14];
    const float* W2   = (const float*)d_in[15];
    const float* b2   = (const float*)d_in[16];

    // ws layout (bytes). q|k|v|o region (134,217,728 B) is recycled for ffa.
    char* ws = (char*)d_ws;
    u16*  hn  = (u16*)(ws + 0ull);            // 33,554,432  (also hn2)
    u16*  qb  = (u16*)(ws + 33554432ull);     // 33,554,432
    u16*  kb  = (u16*)(ws + 67108864ull);     // 33,554,432
    u16*  vb  = (u16*)(ws + 100663296ull);    // 33,554,432
    u16*  ob  = (u16*)(ws + 134217728ull);    // 33,554,432
    u16*  ffa = (u16*)(ws + 33554432ull);     // 134,217,728 (after o consumed)
    float* h1 = (float*)(ws + 167772160ull);  // 67,108,864
    u16*  wqt = (u16*)(ws + 234881024ull);
    u16*  wkt = (u16*)(ws + 235405312ull);
    u16*  wvt = (u16*)(ws + 235929600ull);
    u16*  wot = (u16*)(ws + 236453888ull);
    u16*  w1t = (u16*)(ws + 236978176ull);    // 2,097,152
    u16*  w2t = (u16*)(ws + 239075328ull);    // 2,097,152

    dim3 blk(256);
    transpose_cvt<<<dim3(8, 8),  blk, 0, stream>>>(Wq, wqt, 512, 512);
    transpose_cvt<<<dim3(8, 8),  blk, 0, stream>>>(Wk, wkt, 512, 512);
    transpose_cvt<<<dim3(8, 8),  blk, 0, stream>>>(Wv, wvt, 512, 512);
    transpose_cvt<<<dim3(8, 8),  blk, 0, stream>>>(Wo, wot, 512, 512);
    transpose_cvt<<<dim3(32, 8), blk, 0, stream>>>(W1, w1t, 512, 2048);
    transpose_cvt<<<dim3(8, 32), blk, 0, stream>>>(W2, w2t, 2048, 512);

    ln_kernel<<<32768, blk, 0, stream>>>(x, hn, ln1g, ln1b);

    gemm_kernel<0><<<dim3(4, 256), blk, 0, stream>>>(hn, wqt, bq, nullptr, qb, 32768, 512, 512, 0.125f);
    gemm_kernel<1><<<dim3(4, 256), blk, 0, stream>>>(hn, wkt, bk, nullptr, kb, 32768, 512, 512, 1.f);
    gemm_kernel<2><<<dim3(4, 256), blk, 0, stream>>>(hn, wvt, bv, nullptr, vb, 32768, 512, 512, 1.f);

    attn_kernel<<<dim3(8, 512), blk, 0, stream>>>(qb, kb, vb, ob);

    gemm_kernel<3><<<dim3(4, 256), blk, 0, stream>>>(ob, wot, bo, x, h1, 32768, 512, 512, 1.f);

    ln_kernel<<<32768, blk, 0, stream>>>(h1, hn, ln3g, ln3b);

    gemm_kernel<4><<<dim3(16, 256), blk, 0, stream>>>(hn, w1t, b1, nullptr, ffa, 32768, 2048, 512, 1.f);
    gemm_kernel<3><<<dim3(4, 256), blk, 0, stream>>>(ffa, w2t, b2, h1, (float*)d_out, 32768, 512, 2048, 1.f);
}

// Round 4
// 658.303 us; speedup vs baseline: 1.2958x; 1.0568x over previous
//
#include <hip/hip_runtime.h>
#include <math.h>

typedef unsigned short u16;
typedef __attribute__((ext_vector_type(8))) short bf16x8;
typedef __attribute__((ext_vector_type(4))) float f32x4;

#define MFMA16(a, b, c) __builtin_amdgcn_mfma_f32_16x16x32_bf16((a), (b), (c), 0, 0, 0)

__device__ __forceinline__ u16 f2bf(float f) {
    union { float f; unsigned u; } v; v.f = f;
    unsigned u = v.u;
    unsigned r = (u + 0x7FFFu + ((u >> 16) & 1u)) >> 16;
    return (u16)r;
}

// pack two floats -> (bf16(hi)<<16)|bf16(lo), round-half-up, one v_perm_b32
__device__ __forceinline__ unsigned pack_bf16(float lo, float hi) {
    union { float f; unsigned u; } a, b; a.f = lo; b.f = hi;
    return __builtin_amdgcn_perm(b.u + 0x8000u, a.u + 0x8000u, 0x07060302u);
}

__device__ __forceinline__ float fexp2(float x) {
#if __has_builtin(__builtin_amdgcn_exp2f)
    return __builtin_amdgcn_exp2f(x);
#else
    return __expf(x * 0.6931471805599453f);
#endif
}

// async 16B/lane global->LDS DMA. LDS dest must be lane-linear (base + lane*16).
__device__ __forceinline__ void gl_lds16(const u16* g, u16* l) {
    __builtin_amdgcn_global_load_lds(
        (const __attribute__((address_space(1))) unsigned*)g,
        (__attribute__((address_space(3))) unsigned*)l, 16, 0, 0);
}

// ---------------- weight transpose + fp32->bf16 convert ----------------
__global__ __launch_bounds__(256) void transpose_cvt(const float* __restrict__ src,
                                                     u16* __restrict__ dst, int K, int N) {
    __shared__ float tile[64][65];
    int n0 = blockIdx.x * 64, k0 = blockIdx.y * 64;
    int tx = threadIdx.x & 63, ty = threadIdx.x >> 6;
    #pragma unroll
    for (int i = ty; i < 64; i += 4)
        tile[i][tx] = src[(size_t)(k0 + i) * N + n0 + tx];
    __syncthreads();
    #pragma unroll
    for (int i = ty; i < 64; i += 4)
        dst[(size_t)(n0 + i) * K + k0 + tx] = f2bf(tile[tx][i]);
}

// ---------------- layernorm: fp32 in -> bf16 out, rows of 512 ----------------
__global__ __launch_bounds__(256) void ln_kernel(const float* __restrict__ in,
                                                 u16* __restrict__ out,
                                                 const float* __restrict__ g,
                                                 const float* __restrict__ b) {
    int row = blockIdx.x;
    const float* rp = in + (size_t)row * 512;
    int t = threadIdx.x;
    float2 v = *(const float2*)(rp + t * 2);
    float s = v.x + v.y;
    float sq = v.x * v.x + v.y * v.y;
    #pragma unroll
    for (int off = 32; off > 0; off >>= 1) {
        s  += __shfl_down(s, off, 64);
        sq += __shfl_down(sq, off, 64);
    }
    __shared__ float red[8];
    __shared__ float stat[2];
    int wid = t >> 6;
    if ((t & 63) == 0) { red[wid] = s; red[wid + 4] = sq; }
    __syncthreads();
    if (t == 0) {
        float S = red[0] + red[1] + red[2] + red[3];
        float Q = red[4] + red[5] + red[6] + red[7];
        float mu = S * (1.0f / 512.0f);
        float var = Q * (1.0f / 512.0f) - mu * mu;
        stat[0] = mu;
        stat[1] = rsqrtf(var + 1e-5f);
    }
    __syncthreads();
    float mu = stat[0], inv = stat[1];
    int c = t * 2;
    float2 gv = *(const float2*)(g + c);
    float2 bv = *(const float2*)(b + c);
    ushort2 ov;
    ov.x = f2bf((v.x - mu) * inv * gv.x + bv.x);
    ov.y = f2bf((v.y - mu) * inv * gv.y + bv.y);
    *(ushort2*)(out + (size_t)row * 512 + c) = ov;
}

// ======== fused QKV GEMM: one dispatch, 12 n-tiles (4 q | 4 k | 4 v) ========
// A: hn bf16 [32768][512]; wXt: bf16 [512][512] pre-transposed.
// q/k epilogue: bias + RoPE, head layout [bc][h][s][d]; q also *SCLQ.
// v epilogue: bias, transposed head layout [bc][h][d][s].
__global__ __launch_bounds__(256) void qkv_kernel(
    const u16* __restrict__ A,
    const u16* __restrict__ wqt, const u16* __restrict__ wkt, const u16* __restrict__ wvt,
    const float* __restrict__ bqp, const float* __restrict__ bkp, const float* __restrict__ bvp,
    u16* __restrict__ qb, u16* __restrict__ kb, u16* __restrict__ vb, float sclq)
{
    __shared__ u16 lA[2][128 * 32];
    __shared__ u16 lB[2][128 * 32];
    const int K = 512;
    int flat = blockIdx.y * gridDim.x + blockIdx.x;   // grid (12, 256)
    int xcd = flat & 7, slot = flat >> 3;
    int mt = xcd * 32 + slot / 12;
    int nt = slot % 12;
    int mode = nt >> 2;                                // 0=q 1=k 2=v
    int m0 = mt * 128, n0 = (nt & 3) * 128;
    const u16* Bt = (mode == 0) ? wqt : (mode == 1) ? wkt : wvt;
    const float* bias = (mode == 0) ? bqp : (mode == 1) ? bkp : bvp;
    u16* outp = (mode == 0) ? qb : (mode == 1) ? kb : vb;

    int t = threadIdx.x;
    int wid = t >> 6, lane = t & 63, lm = lane & 15, lq = lane >> 4;
    int wm = (wid >> 1) * 64, wn = (wid & 1) * 64;
    const f32x4 zero = {0.f, 0.f, 0.f, 0.f};
    f32x4 acc[4][4];
    #pragma unroll
    for (int i = 0; i < 4; ++i)
        #pragma unroll
        for (int j = 0; j < 4; ++j) acc[i][j] = zero;

    int rr = t >> 2, cc = (t & 3) * 8;
    const u16* Ab = A + (size_t)(m0 + rr) * K + cc;
    const u16* Bb = Bt + (size_t)(n0 + rr) * K + cc;
    size_t pstep = (size_t)64 * K;
    int ldst = t * 8;

    for (int k0 = 0; k0 < K; k0 += 64) {
        #pragma unroll
        for (int h = 0; h < 2; ++h)
            #pragma unroll
            for (int p = 0; p < 2; ++p) {
                gl_lds16(Ab + k0 + h * 32 + p * pstep, lA[h] + p * 2048 + ldst);
                gl_lds16(Bb + k0 + h * 32 + p * pstep, lB[h] + p * 2048 + ldst);
            }
        __syncthreads();
        #pragma unroll
        for (int h = 0; h < 2; ++h) {
            bf16x8 af[4], bg[4];
            #pragma unroll
            for (int i = 0; i < 4; ++i) af[i] = *(const bf16x8*)&lA[h][(wm + i * 16 + lm) * 32 + lq * 8];
            #pragma unroll
            for (int i = 0; i < 4; ++i) bg[i] = *(const bf16x8*)&lB[h][(wn + i * 16 + lm) * 32 + lq * 8];
            #pragma unroll
            for (int i = 0; i < 4; ++i)
                #pragma unroll
                for (int j = 0; j < 4; ++j)
                    acc[i][j] = MFMA16(af[i], bg[j], acc[i][j]);
        }
        __syncthreads();
    }

    if (mode < 2) {   // q/k: RoPE + head layout
        float bv0 = bias[n0 + wn + 0 * 16 + lm];
        float bv1 = bias[n0 + wn + 1 * 16 + lm];
        float bv2 = bias[n0 + wn + 2 * 16 + lm];
        float bv3 = bias[n0 + wn + 3 * 16 + lm];
        float its = __expf((float)lm * -0.28782313662425572f);  // 10000^(-lm/32)
        float scl = (mode == 0) ? sclq : 1.f;
        #pragma unroll
        for (int i = 0; i < 4; ++i) {
            #pragma unroll
            for (int r = 0; r < 4; ++r) {
                int gm = m0 + wm + i * 16 + lq * 4 + r;
                int s = gm & 511;
                float ang = (float)s * its;
                float sn = __sinf(ang), cs = __cosf(ang);
                float x1 = acc[i][0][r] + bv0;
                float x2 = acc[i][2][r] + bv2;
                float y0 = (x1 * cs - x2 * sn) * scl;
                float y2 = (x2 * cs + x1 * sn) * scl;
                float y1 = (acc[i][1][r] + bv1) * scl;
                float y3 = (acc[i][3][r] + bv3) * scl;
                size_t base = ((size_t)(gm >> 9)) * 262144 + (size_t)((n0 + wn) >> 6) * 32768
                            + (size_t)s * 64 + lm;
                outp[base +  0] = f2bf(y0);
                outp[base + 16] = f2bf(y1);
                outp[base + 32] = f2bf(y2);
                outp[base + 48] = f2bf(y3);
            }
        }
    } else {          // v: transposed head layout [bc][h][d][s]
        #pragma unroll
        for (int i = 0; i < 4; ++i) {
            #pragma unroll
            for (int j = 0; j < 4; ++j) {
                int gn = n0 + wn + j * 16 + lm;
                float bvv = bias[gn];
                #pragma unroll
                for (int r = 0; r < 4; ++r) {
                    int gm = m0 + wm + i * 16 + lq * 4 + r;
                    float v = acc[i][j][r] + bvv;
                    size_t idx = ((size_t)(gm >> 9)) * 262144 + (size_t)(gn >> 6) * 32768
                               + (size_t)(gn & 63) * 512 + (gm & 511);
                    outp[idx] = f2bf(v);
                }
            }
        }
    }
}

// ---------------- bf16 MFMA GEMM, 128x128 tile, BK=64, DMA staging ----------
// MODE 3: out fp32 row-major, v=acc+bias+res
// MODE 4: out bf16 row-major, v=gelu(acc+bias)
template<int MODE>
__global__ __launch_bounds__(256) void gemm_kernel(
    const u16* __restrict__ A, const u16* __restrict__ Bt,
    const float* __restrict__ bias, const float* __restrict__ res,
    void* __restrict__ outp, int M, int N, int K)
{
    __shared__ u16 lA[2][128 * 32];
    __shared__ u16 lB[2][128 * 32];
    int flat = blockIdx.y * gridDim.x + blockIdx.x;
    int xcd = flat & 7, slot = flat >> 3;
    int nb = gridDim.x;
    int mper = gridDim.y >> 3;
    int mt = xcd * mper + slot / nb;
    int nt = slot % nb;
    int m0 = mt * 128, n0 = nt * 128;

    int t = threadIdx.x;
    int wid = t >> 6, lane = t & 63, lm = lane & 15, lq = lane >> 4;
    int wm = (wid >> 1) * 64, wn = (wid & 1) * 64;
    const f32x4 zero = {0.f, 0.f, 0.f, 0.f};
    f32x4 acc[4][4];
    #pragma unroll
    for (int i = 0; i < 4; ++i)
        #pragma unroll
        for (int j = 0; j < 4; ++j) acc[i][j] = zero;

    int rr = t >> 2, cc = (t & 3) * 8;
    const u16* Ab = A + (size_t)(m0 + rr) * K + cc;
    const u16* Bb = Bt + (size_t)(n0 + rr) * K + cc;
    size_t pstep = (size_t)64 * K;
    int ldst = t * 8;

    for (int k0 = 0; k0 < K; k0 += 64) {
        #pragma unroll
        for (int h = 0; h < 2; ++h)
            #pragma unroll
            for (int p = 0; p < 2; ++p) {
                gl_lds16(Ab + k0 + h * 32 + p * pstep, lA[h] + p * 2048 + ldst);
                gl_lds16(Bb + k0 + h * 32 + p * pstep, lB[h] + p * 2048 + ldst);
            }
        __syncthreads();
        #pragma unroll
        for (int h = 0; h < 2; ++h) {
            bf16x8 af[4], bg[4];
            #pragma unroll
            for (int i = 0; i < 4; ++i) af[i] = *(const bf16x8*)&lA[h][(wm + i * 16 + lm) * 32 + lq * 8];
            #pragma unroll
            for (int i = 0; i < 4; ++i) bg[i] = *(const bf16x8*)&lB[h][(wn + i * 16 + lm) * 32 + lq * 8];
            #pragma unroll
            for (int i = 0; i < 4; ++i)
                #pragma unroll
                for (int j = 0; j < 4; ++j)
                    acc[i][j] = MFMA16(af[i], bg[j], acc[i][j]);
        }
        __syncthreads();
    }

    #pragma unroll
    for (int i = 0; i < 4; ++i) {
        #pragma unroll
        for (int j = 0; j < 4; ++j) {
            int gn = n0 + wn + j * 16 + lm;
            float bv = bias[gn];
            #pragma unroll
            for (int r = 0; r < 4; ++r) {
                int gm = m0 + wm + i * 16 + lq * 4 + r;
                float v = acc[i][j][r] + bv;
                if (MODE == 3) {
                    size_t idx = (size_t)gm * N + gn;
                    ((float*)outp)[idx] = v + res[idx];
                } else {
                    float gl = 0.5f * v * (1.f + erff(v * 0.70710678118654752f));
                    ((u16*)outp)[(size_t)gm * N + gn] = f2bf(gl);
                }
            }
        }
    }
}

// ---------------- flash attention, transposed-S formulation ----------------
// q,k: bf16 [nh][s=512][hd=64]; vt: bf16 [nh][hd=64][s=512]
// Scores computed as S^T = K Q^T (C cols = queries -> softmax register-local).
// PV as O^T = V^T P^T.  q pre-scaled by 0.125*log2(e): softmax in base-2.
// o out: bf16 [32768][512] row-major (proj layout)
__global__ __launch_bounds__(256) void attn_kernel(
    const u16* __restrict__ q, const u16* __restrict__ k,
    const u16* __restrict__ vt, u16* __restrict__ o)
{
    int flat = blockIdx.y * gridDim.x + blockIdx.x;   // grid (8,512)
    int xcd = flat & 7, slot = flat >> 3;
    int nh = xcd * 64 + (slot >> 3);
    int qt = slot & 7;
    const u16* Qb = q + (size_t)nh * 32768 + (size_t)qt * 4096;
    const u16* Kb = k + (size_t)nh * 32768;
    const u16* Vb = vt + (size_t)nh * 32768;
    __shared__ u16 lQ[64][72], lK[64][72], lV[64][72];
    __shared__ u16 lP[4][16][72];
    int t = threadIdx.x, wid = t >> 6, lane = t & 63, lm = lane & 15, lq = lane >> 4;

    #pragma unroll
    for (int p = 0; p < 2; ++p) {
        int idx = p * 256 + t, row = idx >> 3, ch = (idx & 7) * 8;
        *(uint4*)&lQ[row][ch] = *(const uint4*)(Qb + (size_t)row * 64 + ch);
    }
    const f32x4 zero = {0.f, 0.f, 0.f, 0.f};
    f32x4 Oacc[4];
    #pragma unroll
    for (int i = 0; i < 4; ++i) Oacc[i] = zero;
    float mo = -INFINITY, l = 0.f;    // scalars: this lane's query is w*16+lm

    for (int kt = 0; kt < 8; ++kt) {
        #pragma unroll
        for (int p = 0; p < 2; ++p) {
            int idx = p * 256 + t, row = idx >> 3, ch = (idx & 7) * 8;
            *(uint4*)&lK[row][ch] = *(const uint4*)(Kb + (size_t)(kt * 64 + row) * 64 + ch);
            *(uint4*)&lV[row][ch] = *(const uint4*)(Vb + (size_t)row * 512 + kt * 64 + ch);
        }
        __syncthreads();
        // S^T = K Q^T : A-frag rows=keys, B-frag cols=queries (reg image = A-read of Q)
        bf16x8 bq0 = *(const bf16x8*)&lQ[wid * 16 + lm][lq * 8];
        bf16x8 bq1 = *(const bf16x8*)&lQ[wid * 16 + lm][32 + lq * 8];
        f32x4 sc[4];
        #pragma unroll
        for (int i = 0; i < 4; ++i) {
            bf16x8 a0 = *(const bf16x8*)&lK[i * 16 + lm][lq * 8];
            bf16x8 a1 = *(const bf16x8*)&lK[i * 16 + lm][32 + lq * 8];
            f32x4 z = MFMA16(a0, bq0, zero);
            sc[i] = MFMA16(a1, bq1, z);
        }
        // softmax over keys: 16 in-thread + 2 shfl (lanes differing in lq bits)
        float mx = sc[0][0];
        #pragma unroll
        for (int i = 0; i < 4; ++i)
            #pragma unroll
            for (int r = 0; r < 4; ++r) mx = fmaxf(mx, sc[i][r]);
        mx = fmaxf(mx, __shfl_xor(mx, 16, 64));
        mx = fmaxf(mx, __shfl_xor(mx, 32, 64));
        float mn = fmaxf(mo, mx);
        float al = fexp2(mo - mn);
        float pv[4][4], sum = 0.f;
        #pragma unroll
        for (int i = 0; i < 4; ++i)
            #pragma unroll
            for (int r = 0; r < 4; ++r) { pv[i][r] = fexp2(sc[i][r] - mn); sum += pv[i][r]; }
        sum += __shfl_xor(sum, 16, 64);
        sum += __shfl_xor(sum, 32, 64);
        l = l * al + sum;
        mo = mn;
        #pragma unroll
        for (int dn = 0; dn < 4; ++dn) Oacc[dn] *= al;
        // P (layout [q][key]) to LDS: 4x 8B packed stores per lane
        #pragma unroll
        for (int i = 0; i < 4; ++i) {
            uint2 w2;
            w2.x = pack_bf16(pv[i][0], pv[i][1]);
            w2.y = pack_bf16(pv[i][2], pv[i][3]);
            *(uint2*)&lP[wid][lm][i * 16 + lq * 4] = w2;
        }
        // O^T += V^T P^T : A-frag rows=d from lV, B-frag cols=queries from lP
        bf16x8 bp0 = *(const bf16x8*)&lP[wid][lm][lq * 8];
        bf16x8 bp1 = *(const bf16x8*)&lP[wid][lm][32 + lq * 8];
        #pragma unroll
        for (int dn = 0; dn < 4; ++dn) {
            bf16x8 a0 = *(const bf16x8*)&lV[dn * 16 + lm][lq * 8];
            bf16x8 a1 = *(const bf16x8*)&lV[dn * 16 + lm][32 + lq * 8];
            Oacc[dn] = MFMA16(a0, bp0, Oacc[dn]);
            Oacc[dn] = MFMA16(a1, bp1, Oacc[dn]);
        }
        __syncthreads();
    }
    // O^T C-layout: col=lm=query, row=lq*4+r = d within dn tile
    int bc = nh >> 3, h = nh & 7;
    float inv = 1.f / l;
    size_t orow = ((size_t)(bc * 512 + qt * 64 + wid * 16 + lm)) * 512 + h * 64;
    #pragma unroll
    for (int dn = 0; dn < 4; ++dn) {
        uint2 w2;
        w2.x = pack_bf16(Oacc[dn][0] * inv, Oacc[dn][1] * inv);
        w2.y = pack_bf16(Oacc[dn][2] * inv, Oacc[dn][3] * inv);
        *(uint2*)(o + orow + dn * 16 + lq * 4) = w2;
    }
}

extern "C" void kernel_launch(void* const* d_in, const int* in_sizes, int n_in,
                              void* d_out, int out_size, void* d_ws, size_t ws_size,
                              hipStream_t stream) {
    const float* x    = (const float*)d_in[0];
    const float* Wq   = (const float*)d_in[1];
    const float* bq   = (const float*)d_in[2];
    const float* Wk   = (const float*)d_in[3];
    const float* bk   = (const float*)d_in[4];
    const float* Wv   = (const float*)d_in[5];
    const float* bv   = (const float*)d_in[6];
    const float* Wo   = (const float*)d_in[7];
    const float* bo   = (const float*)d_in[8];
    const float* ln1g = (const float*)d_in[9];
    const float* ln1b = (const float*)d_in[10];
    const float* ln3g = (const float*)d_in[11];
    const float* ln3b = (const float*)d_in[12];
    const float* W1   = (const float*)d_in[13];
    const float* b1   = (const float*)d_in[14];
    const float* W2   = (const float*)d_in[15];
    const float* b2   = (const float*)d_in[16];

    char* ws = (char*)d_ws;
    u16*  hn  = (u16*)(ws + 0ull);            // 33,554,432  (also hn2)
    u16*  qb  = (u16*)(ws + 33554432ull);     // 33,554,432
    u16*  kb  = (u16*)(ws + 67108864ull);     // 33,554,432
    u16*  vb  = (u16*)(ws + 100663296ull);    // 33,554,432
    u16*  ob  = (u16*)(ws + 134217728ull);    // 33,554,432
    u16*  ffa = (u16*)(ws + 33554432ull);     // 134,217,728 (after o consumed)
    float* h1 = (float*)(ws + 167772160ull);  // 67,108,864
    u16*  wqt = (u16*)(ws + 234881024ull);
    u16*  wkt = (u16*)(ws + 235405312ull);
    u16*  wvt = (u16*)(ws + 235929600ull);
    u16*  wot = (u16*)(ws + 236453888ull);
    u16*  w1t = (u16*)(ws + 236978176ull);    // 2,097,152
    u16*  w2t = (u16*)(ws + 239075328ull);    // 2,097,152

    dim3 blk(256);
    transpose_cvt<<<dim3(8, 8),  blk, 0, stream>>>(Wq, wqt, 512, 512);
    transpose_cvt<<<dim3(8, 8),  blk, 0, stream>>>(Wk, wkt, 512, 512);
    transpose_cvt<<<dim3(8, 8),  blk, 0, stream>>>(Wv, wvt, 512, 512);
    transpose_cvt<<<dim3(8, 8),  blk, 0, stream>>>(Wo, wot, 512, 512);
    transpose_cvt<<<dim3(32, 8), blk, 0, stream>>>(W1, w1t, 512, 2048);
    transpose_cvt<<<dim3(8, 32), blk, 0, stream>>>(W2, w2t, 2048, 512);

    ln_kernel<<<32768, blk, 0, stream>>>(x, hn, ln1g, ln1b);

    // q scale folds HD^-0.5 and log2(e) (softmax computed base-2)
    qkv_kernel<<<dim3(12, 256), blk, 0, stream>>>(hn, wqt, wkt, wvt, bq, bk, bv,
                                                  qb, kb, vb, 0.125f * 1.4426950408889634f);

    attn_kernel<<<dim3(8, 512), blk, 0, stream>>>(qb, kb, vb, ob);

    gemm_kernel<3><<<dim3(4, 256), blk, 0, stream>>>(ob, wot, bo, x, h1, 32768, 512, 512);

    ln_kernel<<<32768, blk, 0, stream>>>(h1, hn, ln3g, ln3b);

    gemm_kernel<4><<<dim3(16, 256), blk, 0, stream>>>(hn, w1t, b1, nullptr, ffa, 32768, 2048, 512);
    gemm_kernel<3><<<dim3(4, 256), blk, 0, stream>>>(ffa, w2t, b2, h1, (float*)d_out, 32768, 512, 2048);
}

// Round 5
// 637.240 us; speedup vs baseline: 1.3387x; 1.0331x over previous
//
#include <hip/hip_runtime.h>
#include <math.h>

typedef unsigned short u16;
typedef __attribute__((ext_vector_type(8))) short bf16x8;
typedef __attribute__((ext_vector_type(4))) float f32x4;

#define MFMA16(a, b, c) __builtin_amdgcn_mfma_f32_16x16x32_bf16((a), (b), (c), 0, 0, 0)

__device__ __forceinline__ u16 f2bf(float f) {
    union { float f; unsigned u; } v; v.f = f;
    unsigned u = v.u;
    unsigned r = (u + 0x7FFFu + ((u >> 16) & 1u)) >> 16;
    return (u16)r;
}

// pack two floats -> (bf16(hi)<<16)|bf16(lo), round-half-up, one v_perm_b32
__device__ __forceinline__ unsigned pack_bf16(float lo, float hi) {
    union { float f; unsigned u; } a, b; a.f = lo; b.f = hi;
    return __builtin_amdgcn_perm(b.u + 0x8000u, a.u + 0x8000u, 0x07060302u);
}

__device__ __forceinline__ float fexp2(float x) {
#if __has_builtin(__builtin_amdgcn_exp2f)
    return __builtin_amdgcn_exp2f(x);
#else
    return __expf(x * 0.6931471805599453f);
#endif
}

// async 16B/lane global->LDS DMA. LDS dest must be lane-linear (base + lane*16).
__device__ __forceinline__ void gl_lds16(const u16* g, u16* l) {
    __builtin_amdgcn_global_load_lds(
        (const __attribute__((address_space(1))) unsigned*)g,
        (__attribute__((address_space(3))) unsigned*)l, 16, 0, 0);
}

// -------- all-weights transpose + fp32->bf16 convert, single dispatch --------
// flat blocks: [0,256) = Wq/Wk/Wv/Wo (64 each), [256,512) W1, [512,768) W2
__global__ __launch_bounds__(256) void transpose_cvt_all(
    const float* __restrict__ Wq, const float* __restrict__ Wk,
    const float* __restrict__ Wv, const float* __restrict__ Wo,
    const float* __restrict__ W1, const float* __restrict__ W2,
    u16* __restrict__ wqt, u16* __restrict__ wkt, u16* __restrict__ wvt,
    u16* __restrict__ wot, u16* __restrict__ w1t, u16* __restrict__ w2t)
{
    __shared__ float tile[64][65];
    int fb = blockIdx.x;
    const float* src; u16* dst; int K, N, bx, by;
    if (fb < 256) {
        int w = fb >> 6, b = fb & 63;
        src = (w == 0) ? Wq : (w == 1) ? Wk : (w == 2) ? Wv : Wo;
        dst = (w == 0) ? wqt : (w == 1) ? wkt : (w == 2) ? wvt : wot;
        K = 512; N = 512; bx = b & 7; by = b >> 3;
    } else if (fb < 512) {
        int b = fb - 256; src = W1; dst = w1t; K = 512; N = 2048; bx = b & 31; by = b >> 5;
    } else {
        int b = fb - 512; src = W2; dst = w2t; K = 2048; N = 512; bx = b & 7; by = b >> 3;
    }
    int n0 = bx * 64, k0 = by * 64;
    int tx = threadIdx.x & 63, ty = threadIdx.x >> 6;
    #pragma unroll
    for (int i = ty; i < 64; i += 4)
        tile[i][tx] = src[(size_t)(k0 + i) * N + n0 + tx];
    __syncthreads();
    #pragma unroll
    for (int i = ty; i < 64; i += 4)
        dst[(size_t)(n0 + i) * K + k0 + tx] = f2bf(tile[tx][i]);
}

// ---------------- layernorm: fp32 in -> bf16 out, rows of 512 ----------------
__global__ __launch_bounds__(256) void ln_kernel(const float* __restrict__ in,
                                                 u16* __restrict__ out,
                                                 const float* __restrict__ g,
                                                 const float* __restrict__ b) {
    int row = blockIdx.x;
    const float* rp = in + (size_t)row * 512;
    int t = threadIdx.x;
    float2 v = *(const float2*)(rp + t * 2);
    float s = v.x + v.y;
    float sq = v.x * v.x + v.y * v.y;
    #pragma unroll
    for (int off = 32; off > 0; off >>= 1) {
        s  += __shfl_down(s, off, 64);
        sq += __shfl_down(sq, off, 64);
    }
    __shared__ float red[8];
    __shared__ float stat[2];
    int wid = t >> 6;
    if ((t & 63) == 0) { red[wid] = s; red[wid + 4] = sq; }
    __syncthreads();
    if (t == 0) {
        float S = red[0] + red[1] + red[2] + red[3];
        float Q = red[4] + red[5] + red[6] + red[7];
        float mu = S * (1.0f / 512.0f);
        float var = Q * (1.0f / 512.0f) - mu * mu;
        stat[0] = mu;
        stat[1] = rsqrtf(var + 1e-5f);
    }
    __syncthreads();
    float mu = stat[0], inv = stat[1];
    int c = t * 2;
    float2 gv = *(const float2*)(g + c);
    float2 bv = *(const float2*)(b + c);
    ushort2 ov;
    ov.x = f2bf((v.x - mu) * inv * gv.x + bv.x);
    ov.y = f2bf((v.y - mu) * inv * gv.y + bv.y);
    *(ushort2*)(out + (size_t)row * 512 + c) = ov;
}

// ======== fused QKV GEMM: one dispatch, 12 n-tiles (4 q | 4 k | 4 v) ========
__global__ __launch_bounds__(256) void qkv_kernel(
    const u16* __restrict__ A,
    const u16* __restrict__ wqt, const u16* __restrict__ wkt, const u16* __restrict__ wvt,
    const float* __restrict__ bqp, const float* __restrict__ bkp, const float* __restrict__ bvp,
    u16* __restrict__ qb, u16* __restrict__ kb, u16* __restrict__ vb, float sclq)
{
    __shared__ u16 lA[2][128 * 32];
    __shared__ u16 lB[2][128 * 32];
    const int K = 512;
    int flat = blockIdx.y * gridDim.x + blockIdx.x;   // grid (12, 256)
    int xcd = flat & 7, slot = flat >> 3;
    int mt = xcd * 32 + slot / 12;
    int nt = slot % 12;
    int mode = nt >> 2;                                // 0=q 1=k 2=v
    int m0 = mt * 128, n0 = (nt & 3) * 128;
    const u16* Bt = (mode == 0) ? wqt : (mode == 1) ? wkt : wvt;
    const float* bias = (mode == 0) ? bqp : (mode == 1) ? bkp : bvp;
    u16* outp = (mode == 0) ? qb : (mode == 1) ? kb : vb;

    int t = threadIdx.x;
    int wid = t >> 6, lane = t & 63, lm = lane & 15, lq = lane >> 4;
    int wm = (wid >> 1) * 64, wn = (wid & 1) * 64;
    const f32x4 zero = {0.f, 0.f, 0.f, 0.f};
    f32x4 acc[4][4];
    #pragma unroll
    for (int i = 0; i < 4; ++i)
        #pragma unroll
        for (int j = 0; j < 4; ++j) acc[i][j] = zero;

    int rr = t >> 2, cc = (t & 3) * 8;
    const u16* Ab = A + (size_t)(m0 + rr) * K + cc;
    const u16* Bb = Bt + (size_t)(n0 + rr) * K + cc;
    size_t pstep = (size_t)64 * K;
    int ldst = t * 8;

    for (int k0 = 0; k0 < K; k0 += 64) {
        #pragma unroll
        for (int h = 0; h < 2; ++h)
            #pragma unroll
            for (int p = 0; p < 2; ++p) {
                gl_lds16(Ab + k0 + h * 32 + p * pstep, lA[h] + p * 2048 + ldst);
                gl_lds16(Bb + k0 + h * 32 + p * pstep, lB[h] + p * 2048 + ldst);
            }
        __syncthreads();
        #pragma unroll
        for (int h = 0; h < 2; ++h) {
            bf16x8 af[4], bg[4];
            #pragma unroll
            for (int i = 0; i < 4; ++i) af[i] = *(const bf16x8*)&lA[h][(wm + i * 16 + lm) * 32 + lq * 8];
            #pragma unroll
            for (int i = 0; i < 4; ++i) bg[i] = *(const bf16x8*)&lB[h][(wn + i * 16 + lm) * 32 + lq * 8];
            #pragma unroll
            for (int i = 0; i < 4; ++i)
                #pragma unroll
                for (int j = 0; j < 4; ++j)
                    acc[i][j] = MFMA16(af[i], bg[j], acc[i][j]);
        }
        __syncthreads();
    }

    if (mode < 2) {   // q/k: RoPE + head layout
        float bv0 = bias[n0 + wn + 0 * 16 + lm];
        float bv1 = bias[n0 + wn + 1 * 16 + lm];
        float bv2 = bias[n0 + wn + 2 * 16 + lm];
        float bv3 = bias[n0 + wn + 3 * 16 + lm];
        float its = __expf((float)lm * -0.28782313662425572f);  // 10000^(-lm/32)
        float scl = (mode == 0) ? sclq : 1.f;
        #pragma unroll
        for (int i = 0; i < 4; ++i) {
            #pragma unroll
            for (int r = 0; r < 4; ++r) {
                int gm = m0 + wm + i * 16 + lq * 4 + r;
                int s = gm & 511;
                float ang = (float)s * its;
                float sn = __sinf(ang), cs = __cosf(ang);
                float x1 = acc[i][0][r] + bv0;
                float x2 = acc[i][2][r] + bv2;
                float y0 = (x1 * cs - x2 * sn) * scl;
                float y2 = (x2 * cs + x1 * sn) * scl;
                float y1 = (acc[i][1][r] + bv1) * scl;
                float y3 = (acc[i][3][r] + bv3) * scl;
                size_t base = ((size_t)(gm >> 9)) * 262144 + (size_t)((n0 + wn) >> 6) * 32768
                            + (size_t)s * 64 + lm;
                outp[base +  0] = f2bf(y0);
                outp[base + 16] = f2bf(y1);
                outp[base + 32] = f2bf(y2);
                outp[base + 48] = f2bf(y3);
            }
        }
    } else {          // v: transposed head layout [bc][h][d][s]
        #pragma unroll
        for (int i = 0; i < 4; ++i) {
            #pragma unroll
            for (int j = 0; j < 4; ++j) {
                int gn = n0 + wn + j * 16 + lm;
                float bvv = bias[gn];
                #pragma unroll
                for (int r = 0; r < 4; ++r) {
                    int gm = m0 + wm + i * 16 + lq * 4 + r;
                    float v = acc[i][j][r] + bvv;
                    size_t idx = ((size_t)(gm >> 9)) * 262144 + (size_t)(gn >> 6) * 32768
                               + (size_t)(gn & 63) * 512 + (gm & 511);
                    outp[idx] = f2bf(v);
                }
            }
        }
    }
}

// ---------------- bf16 MFMA GEMM, 128x128 tile, BK=64, DMA staging ----------
// MODE 3: out fp32 row-major, v=acc+bias+res
// MODE 4: out bf16 row-major, v=gelu(acc+bias)
template<int MODE>
__global__ __launch_bounds__(256) void gemm_kernel(
    const u16* __restrict__ A, const u16* __restrict__ Bt,
    const float* __restrict__ bias, const float* __restrict__ res,
    void* __restrict__ outp, int M, int N, int K)
{
    __shared__ u16 lA[2][128 * 32];
    __shared__ u16 lB[2][128 * 32];
    int flat = blockIdx.y * gridDim.x + blockIdx.x;
    int xcd = flat & 7, slot = flat >> 3;
    int nb = gridDim.x;
    int mper = gridDim.y >> 3;
    int mt = xcd * mper + slot / nb;
    int nt = slot % nb;
    int m0 = mt * 128, n0 = nt * 128;

    int t = threadIdx.x;
    int wid = t >> 6, lane = t & 63, lm = lane & 15, lq = lane >> 4;
    int wm = (wid >> 1) * 64, wn = (wid & 1) * 64;
    const f32x4 zero = {0.f, 0.f, 0.f, 0.f};
    f32x4 acc[4][4];
    #pragma unroll
    for (int i = 0; i < 4; ++i)
        #pragma unroll
        for (int j = 0; j < 4; ++j) acc[i][j] = zero;

    int rr = t >> 2, cc = (t & 3) * 8;
    const u16* Ab = A + (size_t)(m0 + rr) * K + cc;
    const u16* Bb = Bt + (size_t)(n0 + rr) * K + cc;
    size_t pstep = (size_t)64 * K;
    int ldst = t * 8;

    for (int k0 = 0; k0 < K; k0 += 64) {
        #pragma unroll
        for (int h = 0; h < 2; ++h)
            #pragma unroll
            for (int p = 0; p < 2; ++p) {
                gl_lds16(Ab + k0 + h * 32 + p * pstep, lA[h] + p * 2048 + ldst);
                gl_lds16(Bb + k0 + h * 32 + p * pstep, lB[h] + p * 2048 + ldst);
            }
        __syncthreads();
        #pragma unroll
        for (int h = 0; h < 2; ++h) {
            bf16x8 af[4], bg[4];
            #pragma unroll
            for (int i = 0; i < 4; ++i) af[i] = *(const bf16x8*)&lA[h][(wm + i * 16 + lm) * 32 + lq * 8];
            #pragma unroll
            for (int i = 0; i < 4; ++i) bg[i] = *(const bf16x8*)&lB[h][(wn + i * 16 + lm) * 32 + lq * 8];
            #pragma unroll
            for (int i = 0; i < 4; ++i)
                #pragma unroll
                for (int j = 0; j < 4; ++j)
                    acc[i][j] = MFMA16(af[i], bg[j], acc[i][j]);
        }
        __syncthreads();
    }

    #pragma unroll
    for (int i = 0; i < 4; ++i) {
        #pragma unroll
        for (int j = 0; j < 4; ++j) {
            int gn = n0 + wn + j * 16 + lm;
            float bv = bias[gn];
            #pragma unroll
            for (int r = 0; r < 4; ++r) {
                int gm = m0 + wm + i * 16 + lq * 4 + r;
                float v = acc[i][j][r] + bv;
                if (MODE == 3) {
                    size_t idx = (size_t)gm * N + gn;
                    ((float*)outp)[idx] = v + res[idx];
                } else {
                    float gl = 0.5f * v * (1.f + erff(v * 0.70710678118654752f));
                    ((u16*)outp)[(size_t)gm * N + gn] = f2bf(gl);
                }
            }
        }
    }
}

// ---------------- flash attention, transposed-S, 4 q-subtiles per stage ------
// q,k: bf16 [nh][s=512][hd=64]; vt: bf16 [nh][hd=64][s=512]
// Block handles 256 q rows (4 subtiles of 64): K/V staged once per kt for
// 4x the MFMA per barrier (64 MFMA/wave between barrier pairs).
// Q fragments read directly from global (B-frag image = 16B contiguous).
// o out: bf16 [32768][512] row-major (proj layout)
__global__ __launch_bounds__(256) void attn_kernel(
    const u16* __restrict__ q, const u16* __restrict__ k,
    const u16* __restrict__ vt, u16* __restrict__ o)
{
    int flat = blockIdx.y * gridDim.x + blockIdx.x;   // grid (2,512) = 1024 blocks
    int xcd = flat & 7, slot = flat >> 3;
    int nh = xcd * 64 + (slot >> 1);
    int qt = slot & 1;                                 // 256-row q half
    const u16* Qb = q + (size_t)nh * 32768 + (size_t)qt * 16384;
    const u16* Kb = k + (size_t)nh * 32768;
    const u16* Vb = vt + (size_t)nh * 32768;
    __shared__ u16 lK[64][72], lV[64][72];
    __shared__ u16 lP[4][16][72];
    int t = threadIdx.x, wid = t >> 6, lane = t & 63, lm = lane & 15, lq = lane >> 4;

    // Q fragments: 4 subs x 2 k-halves, hoisted (L2/L1 reads, once per block)
    bf16x8 bq[4][2];
    #pragma unroll
    for (int sub = 0; sub < 4; ++sub) {
        const u16* qr = Qb + (size_t)(sub * 64 + wid * 16 + lm) * 64;
        bq[sub][0] = *(const bf16x8*)(qr + lq * 8);
        bq[sub][1] = *(const bf16x8*)(qr + 32 + lq * 8);
    }

    const f32x4 zero = {0.f, 0.f, 0.f, 0.f};
    f32x4 Oacc[4][4];
    float mo[4], l[4];
    #pragma unroll
    for (int s = 0; s < 4; ++s) {
        mo[s] = -INFINITY; l[s] = 0.f;
        #pragma unroll
        for (int d = 0; d < 4; ++d) Oacc[s][d] = zero;
    }

    for (int kt = 0; kt < 8; ++kt) {
        #pragma unroll
        for (int p = 0; p < 2; ++p) {
            int idx = p * 256 + t, row = idx >> 3, ch = (idx & 7) * 8;
            *(uint4*)&lK[row][ch] = *(const uint4*)(Kb + (size_t)(kt * 64 + row) * 64 + ch);
            *(uint4*)&lV[row][ch] = *(const uint4*)(Vb + (size_t)row * 512 + kt * 64 + ch);
        }
        __syncthreads();
        // hoist K and V A-fragments (reused by all 4 subs)
        bf16x8 aK[4][2], aV[4][2];
        #pragma unroll
        for (int i = 0; i < 4; ++i) {
            aK[i][0] = *(const bf16x8*)&lK[i * 16 + lm][lq * 8];
            aK[i][1] = *(const bf16x8*)&lK[i * 16 + lm][32 + lq * 8];
            aV[i][0] = *(const bf16x8*)&lV[i * 16 + lm][lq * 8];
            aV[i][1] = *(const bf16x8*)&lV[i * 16 + lm][32 + lq * 8];
        }
        #pragma unroll
        for (int sub = 0; sub < 4; ++sub) {
            // S^T = K Q^T : lane owns query col lm (of this wave's 16)
            f32x4 sc[4];
            #pragma unroll
            for (int i = 0; i < 4; ++i) {
                f32x4 z = MFMA16(aK[i][0], bq[sub][0], zero);
                sc[i] = MFMA16(aK[i][1], bq[sub][1], z);
            }
            // softmax over 64 keys: 16 in-thread + 2 shfl
            float mx = sc[0][0];
            #pragma unroll
            for (int i = 0; i < 4; ++i)
                #pragma unroll
                for (int r = 0; r < 4; ++r) mx = fmaxf(mx, sc[i][r]);
            mx = fmaxf(mx, __shfl_xor(mx, 16, 64));
            mx = fmaxf(mx, __shfl_xor(mx, 32, 64));
            float mn = fmaxf(mo[sub], mx);
            float al = fexp2(mo[sub] - mn);
            float pv[4][4], sum = 0.f;
            #pragma unroll
            for (int i = 0; i < 4; ++i)
                #pragma unroll
                for (int r = 0; r < 4; ++r) { pv[i][r] = fexp2(sc[i][r] - mn); sum += pv[i][r]; }
            sum += __shfl_xor(sum, 16, 64);
            sum += __shfl_xor(sum, 32, 64);
            l[sub] = l[sub] * al + sum;
            mo[sub] = mn;
            #pragma unroll
            for (int dn = 0; dn < 4; ++dn) Oacc[sub][dn] *= al;
            // P[q][key] to per-wave LDS region (no barrier needed)
            #pragma unroll
            for (int i = 0; i < 4; ++i) {
                uint2 w2;
                w2.x = pack_bf16(pv[i][0], pv[i][1]);
                w2.y = pack_bf16(pv[i][2], pv[i][3]);
                *(uint2*)&lP[wid][lm][i * 16 + lq * 4] = w2;
            }
            bf16x8 bp0 = *(const bf16x8*)&lP[wid][lm][lq * 8];
            bf16x8 bp1 = *(const bf16x8*)&lP[wid][lm][32 + lq * 8];
            #pragma unroll
            for (int dn = 0; dn < 4; ++dn) {
                Oacc[sub][dn] = MFMA16(aV[dn][0], bp0, Oacc[sub][dn]);
                Oacc[sub][dn] = MFMA16(aV[dn][1], bp1, Oacc[sub][dn]);
            }
        }
        __syncthreads();
    }
    int bc = nh >> 3, h = nh & 7;
    #pragma unroll
    for (int sub = 0; sub < 4; ++sub) {
        float inv = 1.f / l[sub];
        size_t orow = ((size_t)(bc * 512 + qt * 256 + sub * 64 + wid * 16 + lm)) * 512 + h * 64;
        #pragma unroll
        for (int dn = 0; dn < 4; ++dn) {
            uint2 w2;
            w2.x = pack_bf16(Oacc[sub][dn][0] * inv, Oacc[sub][dn][1] * inv);
            w2.y = pack_bf16(Oacc[sub][dn][2] * inv, Oacc[sub][dn][3] * inv);
            *(uint2*)(o + orow + dn * 16 + lq * 4) = w2;
        }
    }
}

extern "C" void kernel_launch(void* const* d_in, const int* in_sizes, int n_in,
                              void* d_out, int out_size, void* d_ws, size_t ws_size,
                              hipStream_t stream) {
    const float* x    = (const float*)d_in[0];
    const float* Wq   = (const float*)d_in[1];
    const float* bq   = (const float*)d_in[2];
    const float* Wk   = (const float*)d_in[3];
    const float* bk   = (const float*)d_in[4];
    const float* Wv   = (const float*)d_in[5];
    const float* bv   = (const float*)d_in[6];
    const float* Wo   = (const float*)d_in[7];
    const float* bo   = (const float*)d_in[8];
    const float* ln1g = (const float*)d_in[9];
    const float* ln1b = (const float*)d_in[10];
    const float* ln3g = (const float*)d_in[11];
    const float* ln3b = (const float*)d_in[12];
    const float* W1   = (const float*)d_in[13];
    const float* b1   = (const float*)d_in[14];
    const float* W2   = (const float*)d_in[15];
    const float* b2   = (const float*)d_in[16];

    char* ws = (char*)d_ws;
    u16*  hn  = (u16*)(ws + 0ull);            // 33,554,432  (also hn2)
    u16*  qb  = (u16*)(ws + 33554432ull);     // 33,554,432
    u16*  kb  = (u16*)(ws + 67108864ull);     // 33,554,432
    u16*  vb  = (u16*)(ws + 100663296ull);    // 33,554,432
    u16*  ob  = (u16*)(ws + 134217728ull);    // 33,554,432
    u16*  ffa = (u16*)(ws + 33554432ull);     // 134,217,728 (after o consumed)
    float* h1 = (float*)(ws + 167772160ull);  // 67,108,864
    u16*  wqt = (u16*)(ws + 234881024ull);
    u16*  wkt = (u16*)(ws + 235405312ull);
    u16*  wvt = (u16*)(ws + 235929600ull);
    u16*  wot = (u16*)(ws + 236453888ull);
    u16*  w1t = (u16*)(ws + 236978176ull);    // 2,097,152
    u16*  w2t = (u16*)(ws + 239075328ull);    // 2,097,152

    dim3 blk(256);
    transpose_cvt_all<<<768, blk, 0, stream>>>(Wq, Wk, Wv, Wo, W1, W2,
                                               wqt, wkt, wvt, wot, w1t, w2t);

    ln_kernel<<<32768, blk, 0, stream>>>(x, hn, ln1g, ln1b);

    // q scale folds HD^-0.5 and log2(e) (softmax computed base-2)
    qkv_kernel<<<dim3(12, 256), blk, 0, stream>>>(hn, wqt, wkt, wvt, bq, bk, bv,
                                                  qb, kb, vb, 0.125f * 1.4426950408889634f);

    attn_kernel<<<dim3(2, 512), blk, 0, stream>>>(qb, kb, vb, ob);

    gemm_kernel<3><<<dim3(4, 256), blk, 0, stream>>>(ob, wot, bo, x, h1, 32768, 512, 512);

    ln_kernel<<<32768, blk, 0, stream>>>(h1, hn, ln3g, ln3b);

    gemm_kernel<4><<<dim3(16, 256), blk, 0, stream>>>(hn, w1t, b1, nullptr, ffa, 32768, 2048, 512);
    gemm_kernel<3><<<dim3(4, 256), blk, 0, stream>>>(ffa, w2t, b2, h1, (float*)d_out, 32768, 512, 2048);
}